// Round 8
// baseline (610.835 us; speedup 1.0000x reference)
//
#include <hip/hip_runtime.h>
#include <math.h>

// ---------------------------------------------------------------------------
// QuantumAutoEncoder. Round 8: GEMM without LDS -- A and B fragment layouts
// match global row-major [row,K] exactly (16B contiguous), so each lane loads
// fragments straight from L2 via global_load_dwordx4. No __syncthreads, no
// vmcnt(0) barrier drain; compiler pipelines the K-loop with fine vmcnt.
// Circuit: R6 config (1 item/wave, DPP/swizzle lane exchanges, readlane
// coefficient broadcast). Batch GEMMs split-K=2, W12 fusion, one prep dispatch.
// ---------------------------------------------------------------------------

#define B_SZ 4096
#define EMB 1024
#define NQ 10
#define NL 3

typedef __bf16 bf16x8 __attribute__((ext_vector_type(8)));
typedef float f32x4 __attribute__((ext_vector_type(4)));
typedef unsigned short u16x8 __attribute__((ext_vector_type(8)));

__device__ __forceinline__ unsigned short f2bf_rne(float f) {
    unsigned int u = __float_as_uint(f);
    u += 0x7FFFu + ((u >> 16) & 1u);
    return (unsigned short)(u >> 16);
}
__device__ __forceinline__ float bf2f(unsigned short h) {
    return __uint_as_float(((unsigned int)h) << 16);
}
__device__ __forceinline__ float lane_bcast(float v, int l) {
    return __uint_as_float(__builtin_amdgcn_readlane(__float_as_uint(v), l));
}

// cross-lane xor-M exchange, cheapest primitive per mask (verified R6):
template<int M>
__device__ __forceinline__ float lane_xor(float v) {
    if constexpr (M == 1)
        return __uint_as_float(__builtin_amdgcn_mov_dpp(__float_as_uint(v), 0xB1, 0xF, 0xF, true));
    else if constexpr (M == 2)
        return __uint_as_float(__builtin_amdgcn_mov_dpp(__float_as_uint(v), 0x4E, 0xF, 0xF, true));
    else if constexpr (M == 8)
        return __uint_as_float(__builtin_amdgcn_mov_dpp(__float_as_uint(v), 0x128, 0xF, 0xF, true));
    else if constexpr (M == 4)
        return __uint_as_float(__builtin_amdgcn_ds_swizzle(__float_as_uint(v), 0x101F));
    else if constexpr (M == 16)
        return __uint_as_float(__builtin_amdgcn_ds_swizzle(__float_as_uint(v), 0x401F));
    else
        return __shfl_xor(v, 32, 64);
}

// ------------------- MFMA GEMM (bf16x3), LDS-free ---------------------------
// C[M,Np] += A[M,Kp] @ Bt[Np,Kp]^T ; A,B stored row-major [row][K] bf16 h/l.
// Fragment for 16x16x32 MFMA: row = tile+ (lane&15), k = z*Ksplit + (lane>>4)*8
// -- 16B contiguous in global. Wave tile 32x64 (2x4 frags), block 128x128.
#define GBM 128
#define GBN 128

__global__ __launch_bounds__(512, 4) void gemm3_mfma(
    const unsigned short* __restrict__ Ah, const unsigned short* __restrict__ Al,
    const unsigned short* __restrict__ Bh, const unsigned short* __restrict__ Bl,
    const float* __restrict__ bias, float* __restrict__ C,
    int Kp, int Np, int Ksplit, size_t zStride)
{
    const int tid = threadIdx.x;
    const int lane = tid & 63;
    const int wv = tid >> 6;
    const int wm = wv >> 1;              // 0..3: 32-row band
    const int wn = wv & 1;               // 0..1: 64-col band
    const int blockRow = blockIdx.y * GBM;
    const int blockCol = blockIdx.x * GBN;
    const int z = blockIdx.z;

    const int kq = (lane >> 4) * 8;      // k-element offset of this lane
    const int m0 = blockRow + wm * 32 + (lane & 15);
    const int n0 = blockCol + wn * 64 + (lane & 15);
    const size_t kbase = (size_t)z * Ksplit + kq;

    // per-fragment element offsets (advance by +32 elems per K step)
    size_t aOff[2], bOff[4];
    #pragma unroll
    for (int i = 0; i < 2; ++i) aOff[i] = (size_t)(m0 + i * 16) * Kp + kbase;
    #pragma unroll
    for (int j = 0; j < 4; ++j) bOff[j] = (size_t)(n0 + j * 16) * Kp + kbase;

    f32x4 acc[2][4];
    #pragma unroll
    for (int i = 0; i < 2; ++i)
        #pragma unroll
        for (int j = 0; j < 4; ++j)
            #pragma unroll
            for (int r = 0; r < 4; ++r) acc[i][j][r] = 0.f;

    const int nsteps = Ksplit / 32;
    #pragma unroll 4
    for (int s = 0; s < nsteps; ++s) {
        const size_t kk = (size_t)s * 32;
        bf16x8 ah[2], al[2], bh[4], bl[4];
        #pragma unroll
        for (int i = 0; i < 2; ++i) {
            ah[i] = *(const bf16x8*)(Ah + aOff[i] + kk);
            al[i] = *(const bf16x8*)(Al + aOff[i] + kk);
        }
        #pragma unroll
        for (int j = 0; j < 4; ++j) {
            bh[j] = *(const bf16x8*)(Bh + bOff[j] + kk);
            bl[j] = *(const bf16x8*)(Bl + bOff[j] + kk);
        }
        #pragma unroll
        for (int j = 0; j < 4; ++j)
            #pragma unroll
            for (int i = 0; i < 2; ++i) {
                acc[i][j] = __builtin_amdgcn_mfma_f32_16x16x32_bf16(al[i], bh[j], acc[i][j], 0, 0, 0);
                acc[i][j] = __builtin_amdgcn_mfma_f32_16x16x32_bf16(ah[i], bl[j], acc[i][j], 0, 0, 0);
                acc[i][j] = __builtin_amdgcn_mfma_f32_16x16x32_bf16(ah[i], bh[j], acc[i][j], 0, 0, 0);
            }
    }

    float* Cz = C + (size_t)z * zStride;
    const bool addB = (z == 0) && (bias != nullptr);
    const int rquad = (lane >> 4) * 4;
    const int cidx = lane & 15;
    #pragma unroll
    for (int i = 0; i < 2; ++i)
        #pragma unroll
        for (int j = 0; j < 4; ++j) {
            #pragma unroll
            for (int r = 0; r < 4; ++r) {
                int row = blockRow + wm * 32 + i * 16 + rquad + r;
                int col = blockCol + wn * 64 + j * 16 + cidx;
                float v = acc[i][j][r];
                if (addB) v += bias[col];
                Cz[(size_t)row * Np + col] = v;
            }
        }
}

// --------------------------- unified prep kernel ---------------------------
__device__ __forceinline__ void tsplit_block(
    const float* __restrict__ W, unsigned short* __restrict__ H, unsigned short* __restrict__ L,
    int K, int N, int Kp, int bx, int by, int tid)
{
    __shared__ float tile[32][33];
    const int tx = tid & 31, ty = tid >> 5;
    const int k0 = bx * 32, n0 = by * 32;
    #pragma unroll
    for (int i = 0; i < 4; ++i) {
        int k = k0 + ty + i * 8, n = n0 + tx;
        tile[ty + i * 8][tx] = (k < K && n < N) ? W[(size_t)k * N + n] : 0.f;
    }
    __syncthreads();
    #pragma unroll
    for (int i = 0; i < 4; ++i) {
        int n = n0 + ty + i * 8, k = k0 + tx;
        float v = tile[tx][ty + i * 8];
        size_t o = (size_t)n * Kp + k;
        unsigned short h = f2bf_rne(v);
        H[o] = h;
        L[o] = f2bf_rne(v - bf2f(h));
    }
}

// grid 9237:
//  [0,1024)      W0 tsplit        [1024,3072) W2 tsplit   [3072,4096) W3 tsplit
//  [4096,5120)   W1 row-split     [5120,9216) inputs row-split (pad 1000->1024)
//  [9216,9232)   b12              [9232,9236) b3 pad      [9236] gate coeffs
__global__ __launch_bounds__(256) void prep_all_kernel(
    const float* __restrict__ W0, unsigned short* __restrict__ Bt0h, unsigned short* __restrict__ Bt0l,
    const float* __restrict__ W2, unsigned short* __restrict__ Bt2h, unsigned short* __restrict__ Bt2l,
    const float* __restrict__ W3, unsigned short* __restrict__ Bt3h, unsigned short* __restrict__ Bt3l,
    const float* __restrict__ W1, unsigned short* __restrict__ W1h, unsigned short* __restrict__ W1l,
    const float* __restrict__ X, unsigned short* __restrict__ Ah, unsigned short* __restrict__ Al,
    const float* __restrict__ b1, const float* __restrict__ b2, float* __restrict__ b12,
    const float* __restrict__ b3, float* __restrict__ b3p,
    const float* __restrict__ wEnc, const float* __restrict__ wDec, float* __restrict__ G)
{
    const int bid = blockIdx.x;
    const int tid = threadIdx.x;
    if (bid < 1024) {
        tsplit_block(W0, Bt0h, Bt0l, 1000, 1024, 1024, bid & 31, bid >> 5, tid);
    } else if (bid < 3072) {
        int b = bid - 1024;
        tsplit_block(W2, Bt2h, Bt2l, 2048, 1024, 2048, b & 63, b >> 6, tid);
    } else if (bid < 4096) {
        int b = bid - 3072;
        tsplit_block(W3, Bt3h, Bt3l, 1024, 1000, 1024, b & 31, b >> 5, tid);
    } else if (bid < 5120) {
        int r = bid - 4096;
        for (int c = tid; c < 2048; c += 256) {
            float v = W1[(size_t)r * 2048 + c];
            unsigned short h = f2bf_rne(v);
            size_t o = (size_t)r * 2048 + c;
            W1h[o] = h;
            W1l[o] = f2bf_rne(v - bf2f(h));
        }
    } else if (bid < 9216) {
        int r = bid - 5120;
        for (int c = tid; c < 1024; c += 256) {
            float v = (c < 1000) ? X[(size_t)r * 1000 + c] : 0.f;
            unsigned short h = f2bf_rne(v);
            size_t o = (size_t)r * 1024 + c;
            Ah[o] = h;
            Al[o] = f2bf_rne(v - bf2f(h));
        }
    } else if (bid < 9232) {
        __shared__ float red[4][64];
        const int tx = tid & 63, ty = tid >> 6;
        const int n = (bid - 9216) * 64 + tx;
        float s = 0.f;
        for (int j = ty * 512; j < (ty + 1) * 512; ++j)
            s += b1[j] * W2[(size_t)j * 1024 + n];
        red[ty][tx] = s;
        __syncthreads();
        if (ty == 0) b12[n] = red[0][tx] + red[1][tx] + red[2][tx] + red[3][tx] + b2[n];
    } else if (bid < 9236) {
        int i = (bid - 9232) * 256 + tid;
        b3p[i] = (i < 1000) ? b3[i] : 0.f;
    } else {
        int g = tid;
        if (g < 60) {
            const float* w = (g < 30) ? (wEnc + g * 3) : (wDec + (g - 30) * 3);
            float* o = G + ((g < 30) ? g : (g - 30 + 64)) * 8;
            float phi = w[0], th = w[1], om = w[2];
            float ch = cosf(0.5f * th), sh = sinf(0.5f * th);
            float ap = 0.5f * (phi + om), am = 0.5f * (phi - om);
            float cap = cosf(ap), sap = sinf(ap);
            float cam = cosf(am), sam = sinf(am);
            o[0] =  cap * ch; o[1] = -sap * ch;
            o[2] = -cam * sh; o[3] = -sam * sh;
            o[4] =  cam * sh; o[5] = -sam * sh;
            o[6] =  cap * ch; o[7] =  sap * ch;
        }
    }
}

// tsplit over the sum of 8 split-K partials: P = 8 x [1024][1024] fp32.
__global__ __launch_bounds__(256) void tsplit8_kernel(
    const float* __restrict__ P, unsigned short* __restrict__ H, unsigned short* __restrict__ L)
{
    __shared__ float tile[32][33];
    const int tid = threadIdx.x;
    const int tx = tid & 31, ty = tid >> 5;
    const int k0 = blockIdx.x * 32, n0 = blockIdx.y * 32;
    #pragma unroll
    for (int i = 0; i < 4; ++i) {
        int k = k0 + ty + i * 8, n = n0 + tx;
        size_t o = (size_t)k * 1024 + n;
        float s = 0.f;
        #pragma unroll
        for (int zz = 0; zz < 8; ++zz) s += P[o + ((size_t)zz << 20)];
        tile[ty + i * 8][tx] = s;
    }
    __syncthreads();
    #pragma unroll
    for (int i = 0; i < 4; ++i) {
        int n = n0 + ty + i * 8, k = k0 + tx;
        float v = tile[tx][ty + i * 8];
        size_t o = (size_t)n * 1024 + k;
        unsigned short h = f2bf_rne(v);
        H[o] = h;
        L[o] = f2bf_rne(v - bf2f(h));
    }
}

// ----------------- register-resident quantum circuit -----------------------
// amp idx = (lane<<4)|reg. Wire q stride S=1<<(9-q); S<16 reg bit, else lane bit.

template<int GATE, int Q>
__device__ __forceinline__ void apply_rot(float (&xr)[16], float (&xi)[16],
                                          const float (&tbl)[8], int lane)
{
    float are = lane_bcast(tbl[0], GATE), aim = lane_bcast(tbl[1], GATE);
    float bre = lane_bcast(tbl[2], GATE), bim = lane_bcast(tbl[3], GATE);
    float cre = lane_bcast(tbl[4], GATE), cim = lane_bcast(tbl[5], GATE);
    float dre = lane_bcast(tbl[6], GATE), dim_ = lane_bcast(tbl[7], GATE);
    constexpr int S = 1 << (9 - Q);
    if constexpr (S < 16) {
        #pragma unroll
        for (int p = 0; p < 8; ++p) {
            int r0 = (p / S) * (2 * S) + (p % S);
            int r1 = r0 + S;
            float x0r = xr[r0], x0i = xi[r0], x1r = xr[r1], x1i = xi[r1];
            xr[r0] = are * x0r - aim * x0i + bre * x1r - bim * x1i;
            xi[r0] = are * x0i + aim * x0r + bre * x1i + bim * x1r;
            xr[r1] = cre * x0r - cim * x0i + dre * x1r - dim_ * x1i;
            xi[r1] = cre * x0i + cim * x0r + dre * x1i + dim_ * x1r;
        }
    } else {
        constexpr int M = S >> 4;
        bool bit = (lane & M) != 0;
        float pre = bit ? dre : are, pim = bit ? dim_ : aim;
        float qre = bit ? cre : bre, qim = bit ? cim : bim;
        #pragma unroll
        for (int r = 0; r < 16; ++r) {
            float ore = lane_xor<M>(xr[r]);
            float oim = lane_xor<M>(xi[r]);
            float nr = pre * xr[r] - pim * xi[r] + qre * ore - qim * oim;
            float ni = pre * xi[r] + pim * xr[r] + qre * oim + qim * ore;
            xr[r] = nr; xi[r] = ni;
        }
    }
}

template<int C, int T>
__device__ __forceinline__ void apply_cnot(float (&xr)[16], float (&xi)[16], int lane)
{
    constexpr int SC = 1 << (9 - C), ST = 1 << (9 - T);
    if constexpr (SC < 16 && ST < 16) {
        #pragma unroll
        for (int r = 0; r < 16; ++r) {
            if ((r & SC) && !(r & ST)) {
                int j = r | ST;
                float t;
                t = xr[r]; xr[r] = xr[j]; xr[j] = t;
                t = xi[r]; xi[r] = xi[j]; xi[j] = t;
            }
        }
    } else if constexpr (SC < 16) {
        constexpr int MT = ST >> 4;
        #pragma unroll
        for (int r = 0; r < 16; ++r) {
            if (r & SC) {
                xr[r] = lane_xor<MT>(xr[r]);
                xi[r] = lane_xor<MT>(xi[r]);
            }
        }
    } else if constexpr (ST < 16) {
        constexpr int MC = SC >> 4;
        bool bit = (lane & MC) != 0;
        #pragma unroll
        for (int r = 0; r < 16; ++r) {
            if (!(r & ST)) {
                int j = r | ST;
                float a0 = xr[r], a1 = xr[j];
                xr[r] = bit ? a1 : a0;  xr[j] = bit ? a0 : a1;
                float b0 = xi[r], b1 = xi[j];
                xi[r] = bit ? b1 : b0;  xi[j] = bit ? b0 : b1;
            }
        }
    } else {
        constexpr int MC = SC >> 4, MT = ST >> 4;
        bool bit = (lane & MC) != 0;
        #pragma unroll
        for (int r = 0; r < 16; ++r) {
            float o = lane_xor<MT>(xr[r]);
            xr[r] = bit ? o : xr[r];
            float oi = lane_xor<MT>(xi[r]);
            xi[r] = bit ? oi : xi[r];
        }
    }
}

template<int L, int Q>
__device__ __forceinline__ void rots(float (&xr)[16], float (&xi)[16],
                                     const float (&tbl)[8], int lane) {
    apply_rot<L * 10 + Q, Q>(xr, xi, tbl, lane);
    if constexpr (Q < 9) rots<L, Q + 1>(xr, xi, tbl, lane);
}
template<int L, int Q>
__device__ __forceinline__ void cnots(float (&xr)[16], float (&xi)[16], int lane) {
    constexpr int R = (L % 9) + 1;
    apply_cnot<Q, (Q + R) % 10>(xr, xi, lane);
    if constexpr (Q < 9) cnots<L, Q + 1>(xr, xi, lane);
}

// X = X0 + X1 (split-K partials) -> circuit -> hi/lo bf16 split probs.
__global__ __launch_bounds__(256, 4) void circuit_reg_kernel(
    const float* __restrict__ X0, const float* __restrict__ X1,
    unsigned short* __restrict__ Ph, unsigned short* __restrict__ Pl,
    const float* __restrict__ G)
{
    const int lane = threadIdx.x & 63;
    const int item = blockIdx.x * 4 + (threadIdx.x >> 6);
    const size_t base = (size_t)item * 1024 + lane * 16;

    float tbl[8];
    {
        const float4* gp = (const float4*)(G + lane * 8);
        float4 t0 = gp[0], t1 = gp[1];
        tbl[0] = t0.x; tbl[1] = t0.y; tbl[2] = t0.z; tbl[3] = t0.w;
        tbl[4] = t1.x; tbl[5] = t1.y; tbl[6] = t1.z; tbl[7] = t1.w;
    }

    float xr[16], xi[16];
    const float4* xb0 = (const float4*)(X0 + base);
    const float4* xb1 = (const float4*)(X1 + base);
    #pragma unroll
    for (int v = 0; v < 4; ++v) {
        float4 f = xb0[v], g = xb1[v];
        xr[v * 4 + 0] = f.x + g.x; xr[v * 4 + 1] = f.y + g.y;
        xr[v * 4 + 2] = f.z + g.z; xr[v * 4 + 3] = f.w + g.w;
    }
    #pragma unroll
    for (int r = 0; r < 16; ++r) xi[r] = 0.f;

    float nrm = 0.f;
    #pragma unroll
    for (int r = 0; r < 16; ++r) nrm += xr[r] * xr[r];
    nrm += lane_xor<1>(nrm);
    nrm += lane_xor<2>(nrm);
    nrm += lane_xor<4>(nrm);
    nrm += lane_xor<8>(nrm);
    nrm += lane_xor<16>(nrm);
    nrm += lane_xor<32>(nrm);
    float inv = 1.0f / sqrtf(nrm);
    #pragma unroll
    for (int r = 0; r < 16; ++r) xr[r] *= inv;

    rots<0, 0>(xr, xi, tbl, lane);  cnots<0, 0>(xr, xi, lane);
    rots<1, 0>(xr, xi, tbl, lane);  cnots<1, 0>(xr, xi, lane);
    rots<2, 0>(xr, xi, tbl, lane);  cnots<2, 0>(xr, xi, lane);

    u16x8 h[2], lo[2];
    #pragma unroll
    for (int r = 0; r < 16; ++r) {
        float p = xr[r] * xr[r] + xi[r] * xi[r];
        unsigned short hh = f2bf_rne(p);
        h[r >> 3][r & 7] = hh;
        lo[r >> 3][r & 7] = f2bf_rne(p - bf2f(hh));
    }
    *(u16x8*)(Ph + base) = h[0];
    *(u16x8*)(Ph + base + 8) = h[1];
    *(u16x8*)(Pl + base) = lo[0];
    *(u16x8*)(Pl + base + 8) = lo[1];
}

// --------------- abs + row-normalize (2 partials, single pass) -------------
__global__ __launch_bounds__(256) void absnorm_kernel(
    const float* __restrict__ P, size_t ZS, float* __restrict__ out, int N)
{
    __shared__ float red[4];
    const int row = blockIdx.x;
    const int tid = threadIdx.x;
    const size_t rb = (size_t)row * 1024 + tid * 4;

    float4 a = *(const float4*)(P + rb);
    float4 b = *(const float4*)(P + ZS + rb);
    float x[4] = { a.x + b.x, a.y + b.y, a.z + b.z, a.w + b.w };

    const int c0 = tid * 4;
    float s = 0.f;
    #pragma unroll
    for (int j = 0; j < 4; ++j) if (c0 + j < N) s += fabsf(x[j]);
    #pragma unroll
    for (int off = 32; off > 0; off >>= 1) s += __shfl_down(s, off);
    if ((tid & 63) == 0) red[tid >> 6] = s;
    __syncthreads();
    float inv = 1.0f / (red[0] + red[1] + red[2] + red[3]);
    #pragma unroll
    for (int j = 0; j < 4; ++j)
        if (c0 + j < N) out[(size_t)row * N + c0 + j] = fabsf(x[j]) * inv;
}

// ---------------------------------------------------------------------------
extern "C" void kernel_launch(void* const* d_in, const int* in_sizes, int n_in,
                              void* d_out, int out_size, void* d_ws, size_t ws_size,
                              hipStream_t stream)
{
    const float* inputs = (const float*)d_in[0];
    const float* wEnc   = (const float*)d_in[1];
    const float* wDec   = (const float*)d_in[2];
    const float* W0     = (const float*)d_in[3];
    const float* b0     = (const float*)d_in[4];
    const float* W1     = (const float*)d_in[5];
    const float* b1     = (const float*)d_in[6];
    const float* W2     = (const float*)d_in[7];
    const float* b2     = (const float*)d_in[8];
    const float* W3     = (const float*)d_in[9];
    const float* b3     = (const float*)d_in[10];
    float* out = (float*)d_out;

    char* w = (char*)d_ws;
    auto alloc = [&](size_t bytes) { char* p = w; w += (bytes + 255) & ~(size_t)255; return p; };

    unsigned short* Bt0h  = (unsigned short*)alloc((size_t)1024 * 1024 * 2);
    unsigned short* Bt0l  = (unsigned short*)alloc((size_t)1024 * 1024 * 2);
    unsigned short* Bt2h  = (unsigned short*)alloc((size_t)1024 * 2048 * 2);
    unsigned short* Bt2l  = (unsigned short*)alloc((size_t)1024 * 2048 * 2);
    unsigned short* Bt3h  = (unsigned short*)alloc((size_t)1024 * 1024 * 2);
    unsigned short* Bt3l  = (unsigned short*)alloc((size_t)1024 * 1024 * 2);
    unsigned short* Bt12h = (unsigned short*)alloc((size_t)1024 * 1024 * 2);
    unsigned short* Bt12l = (unsigned short*)alloc((size_t)1024 * 1024 * 2);
    unsigned short* W1h   = (unsigned short*)alloc((size_t)1024 * 2048 * 2);
    unsigned short* W1l   = (unsigned short*)alloc((size_t)1024 * 2048 * 2);
    float*          b3p   = (float*)alloc(1024 * 4);
    float*          b12   = (float*)alloc(1024 * 4);
    float*          G     = (float*)alloc(2 * 512 * 4);   // enc @ G, dec @ G+512
    unsigned short* Ah    = (unsigned short*)alloc((size_t)B_SZ * 1024 * 2);
    unsigned short* Al    = (unsigned short*)alloc((size_t)B_SZ * 1024 * 2);
    unsigned short* ph    = (unsigned short*)alloc((size_t)B_SZ * 1024 * 2);
    unsigned short* pl    = (unsigned short*)alloc((size_t)B_SZ * 1024 * 2);
    float*          P     = (float*)alloc((size_t)2 * B_SZ * 1024 * 4);  // split-K partials
    float* P12 = P;                 // 8 x [1024x1024] fp32 (32 MB) aliased; dead before G0
    const size_t ZS = (size_t)B_SZ * 1024;

    dim3 blk256(256);

    // ---- per-call prep: ONE dispatch ----
    prep_all_kernel<<<9237, blk256, 0, stream>>>(
        W0, Bt0h, Bt0l, W2, Bt2h, Bt2l, W3, Bt3h, Bt3l, W1, W1h, W1l,
        inputs, Ah, Al, b1, b2, b12, b3, b3p, wEnc, wDec, G);

    // ---- W12 = W1 @ W2 (split-K=8) -> transpose+split -> Bt12 ----
    gemm3_mfma<<<dim3(8, 8, 8), 512, 0, stream>>>(
        W1h, W1l, Bt2h, Bt2l, nullptr, P12, 2048, 1024, 256, (size_t)1 << 20);
    tsplit8_kernel<<<dim3(32, 32), blk256, 0, stream>>>(P12, Bt12h, Bt12l);

    // ---- pipeline (batch GEMMs split-K=2) ----
    gemm3_mfma<<<dim3(8, 32, 2), 512, 0, stream>>>(
        Ah, Al, Bt0h, Bt0l, b0, P, 1024, 1024, 512, ZS);
    circuit_reg_kernel<<<B_SZ / 4, blk256, 0, stream>>>(P, P + ZS, ph, pl, G);
    gemm3_mfma<<<dim3(8, 32, 2), 512, 0, stream>>>(
        ph, pl, Bt12h, Bt12l, b12, P, 1024, 1024, 512, ZS);
    circuit_reg_kernel<<<B_SZ / 4, blk256, 0, stream>>>(P, P + ZS, ph, pl, G + 512);
    gemm3_mfma<<<dim3(8, 32, 2), 512, 0, stream>>>(
        ph, pl, Bt3h, Bt3l, b3p, P, 1024, 1024, 512, ZS);
    absnorm_kernel<<<B_SZ, blk256, 0, stream>>>(P, ZS, out, 1000);
}

// Round 9
// 407.624 us; speedup vs baseline: 1.4985x; 1.4985x over previous
//
#include <hip/hip_runtime.h>
#include <math.h>

// ---------------------------------------------------------------------------
// QuantumAutoEncoder. Round 9: revert R8's LDS-free GEMM (latency-bound,
// 100us) back to the proven global_load_lds staging -- now DOUBLE-BUFFERED
// with raw s_waitcnt vmcnt(4) + s_barrier so next-tile loads stay in flight
// across the barrier (AITER pattern), instead of the vmcnt(0) full drain.
// Circuit: R6 (1 item/wave, DPP/swizzle, readlane coeffs). Split-K=2 batch
// GEMMs, W12 fusion, one prep dispatch, single-pass absnorm.
// ---------------------------------------------------------------------------

#define B_SZ 4096
#define EMB 1024
#define NQ 10
#define NL 3

typedef __bf16 bf16x8 __attribute__((ext_vector_type(8)));
typedef float f32x4 __attribute__((ext_vector_type(4)));
typedef unsigned short u16x8 __attribute__((ext_vector_type(8)));

__device__ __forceinline__ unsigned short f2bf_rne(float f) {
    unsigned int u = __float_as_uint(f);
    u += 0x7FFFu + ((u >> 16) & 1u);
    return (unsigned short)(u >> 16);
}
__device__ __forceinline__ float bf2f(unsigned short h) {
    return __uint_as_float(((unsigned int)h) << 16);
}
__device__ __forceinline__ float lane_bcast(float v, int l) {
    return __uint_as_float(__builtin_amdgcn_readlane(__float_as_uint(v), l));
}

template<int M>
__device__ __forceinline__ float lane_xor(float v) {
    if constexpr (M == 1)
        return __uint_as_float(__builtin_amdgcn_mov_dpp(__float_as_uint(v), 0xB1, 0xF, 0xF, true));
    else if constexpr (M == 2)
        return __uint_as_float(__builtin_amdgcn_mov_dpp(__float_as_uint(v), 0x4E, 0xF, 0xF, true));
    else if constexpr (M == 8)
        return __uint_as_float(__builtin_amdgcn_mov_dpp(__float_as_uint(v), 0x128, 0xF, 0xF, true));
    else if constexpr (M == 4)
        return __uint_as_float(__builtin_amdgcn_ds_swizzle(__float_as_uint(v), 0x101F));
    else if constexpr (M == 16)
        return __uint_as_float(__builtin_amdgcn_ds_swizzle(__float_as_uint(v), 0x401F));
    else
        return __shfl_xor(v, 32, 64);
}

__device__ __forceinline__ void gll16(const void* g, void* l) {
    __builtin_amdgcn_global_load_lds(
        (const __attribute__((address_space(1))) void*)g,
        (__attribute__((address_space(3))) void*)l, 16, 0, 0);
}

// waitcnt imm (gfx9): vmcnt[3:0], expcnt[6:4]=7 (none), lgkmcnt[11:8]=0xF (none)
#define WAITCNT_VM(N) __builtin_amdgcn_s_waitcnt(0x0F70 | (N))

// ---------------- MFMA GEMM (bf16x3), double-buffered LDS ------------------
#define GBM 128
#define GBN 128
#define GBK 32

__global__ __launch_bounds__(512) void gemm3_mfma(
    const unsigned short* __restrict__ Ah, const unsigned short* __restrict__ Al,
    const unsigned short* __restrict__ Bh, const unsigned short* __restrict__ Bl,
    const float* __restrict__ bias, float* __restrict__ C,
    int Kp, int Np, int Ksplit, size_t zStride)
{
    __shared__ __align__(16) char lds[65536];   // 2 x 32KB buffers

    const int tid = threadIdx.x;
    const int lane = tid & 63;
    const int wv = tid >> 6;
    const int wm = wv >> 1;
    const int wn = wv & 1;
    const int blockRow = blockIdx.y * GBM;
    const int blockCol = blockIdx.x * GBN;
    const int z = blockIdx.z;

    const int srow = tid >> 2;
    const int skel = (tid & 3) * 8;
    const size_t aOff = ((size_t)(blockRow + srow) * Kp + skel + (size_t)z * Ksplit) * 2;
    const size_t bOff = ((size_t)(blockCol + srow) * Kp + skel + (size_t)z * Ksplit) * 2;
    const char* aHp = (const char*)Ah + aOff;
    const char* aLp = (const char*)Al + aOff;
    const char* bHp = (const char*)Bh + bOff;
    const char* bLp = (const char*)Bl + bOff;
    const int stageOff = wv * 1024;

    f32x4 acc[2][4];
    #pragma unroll
    for (int i = 0; i < 2; ++i)
        #pragma unroll
        for (int j = 0; j < 4; ++j)
            #pragma unroll
            for (int r = 0; r < 4; ++r) acc[i][j][r] = 0.f;

    const int kq = (lane >> 4) * 16;
    int aFragOff[2], bFragOff[4];
    #pragma unroll
    for (int i = 0; i < 2; ++i) aFragOff[i] = (wm * 32 + i * 16 + (lane & 15)) * 64 + kq;
    #pragma unroll
    for (int j = 0; j < 4; ++j) bFragOff[j] = (wn * 64 + j * 16 + (lane & 15)) * 64 + kq;

    auto stage = [&](int s, int buf) {
        char* base = lds + buf * 32768;
        const size_t kb = (size_t)s * GBK * 2;
        gll16(aHp + kb, base + stageOff);
        gll16(aLp + kb, base + 8192 + stageOff);
        gll16(bHp + kb, base + 16384 + stageOff);
        gll16(bLp + kb, base + 24576 + stageOff);
    };

    const int nsteps = Ksplit / GBK;
    stage(0, 0);
    for (int s = 0; s < nsteps; ++s) {
        const int buf = s & 1;
        if (s + 1 < nsteps) {
            stage(s + 1, buf ^ 1);
            WAITCNT_VM(4);          // wait for this tile; next tile stays in flight
        } else {
            WAITCNT_VM(0);
        }
        __builtin_amdgcn_s_barrier();

        char* base = lds + buf * 32768;
        bf16x8 ah[2], al[2], bh[4], bl[4];
        #pragma unroll
        for (int i = 0; i < 2; ++i) {
            ah[i] = *(const bf16x8*)(base + aFragOff[i]);
            al[i] = *(const bf16x8*)(base + 8192 + aFragOff[i]);
        }
        #pragma unroll
        for (int j = 0; j < 4; ++j) {
            bh[j] = *(const bf16x8*)(base + 16384 + bFragOff[j]);
            bl[j] = *(const bf16x8*)(base + 24576 + bFragOff[j]);
        }
        #pragma unroll
        for (int j = 0; j < 4; ++j)
            #pragma unroll
            for (int i = 0; i < 2; ++i) {
                acc[i][j] = __builtin_amdgcn_mfma_f32_16x16x32_bf16(al[i], bh[j], acc[i][j], 0, 0, 0);
                acc[i][j] = __builtin_amdgcn_mfma_f32_16x16x32_bf16(ah[i], bl[j], acc[i][j], 0, 0, 0);
                acc[i][j] = __builtin_amdgcn_mfma_f32_16x16x32_bf16(ah[i], bh[j], acc[i][j], 0, 0, 0);
            }
        __syncthreads();            // protect buf^1 region before restaging it
    }

    float* Cz = C + (size_t)z * zStride;
    const bool addB = (z == 0) && (bias != nullptr);
    const int rquad = (lane >> 4) * 4;
    const int cidx = lane & 15;
    #pragma unroll
    for (int i = 0; i < 2; ++i)
        #pragma unroll
        for (int j = 0; j < 4; ++j) {
            #pragma unroll
            for (int r = 0; r < 4; ++r) {
                int row = blockRow + wm * 32 + i * 16 + rquad + r;
                int col = blockCol + wn * 64 + j * 16 + cidx;
                float v = acc[i][j][r];
                if (addB) v += bias[col];
                Cz[(size_t)row * Np + col] = v;
            }
        }
}

// --------------------------- unified prep kernel ---------------------------
__device__ __forceinline__ void tsplit_block(
    const float* __restrict__ W, unsigned short* __restrict__ H, unsigned short* __restrict__ L,
    int K, int N, int Kp, int bx, int by, int tid)
{
    __shared__ float tile[32][33];
    const int tx = tid & 31, ty = tid >> 5;
    const int k0 = bx * 32, n0 = by * 32;
    #pragma unroll
    for (int i = 0; i < 4; ++i) {
        int k = k0 + ty + i * 8, n = n0 + tx;
        tile[ty + i * 8][tx] = (k < K && n < N) ? W[(size_t)k * N + n] : 0.f;
    }
    __syncthreads();
    #pragma unroll
    for (int i = 0; i < 4; ++i) {
        int n = n0 + ty + i * 8, k = k0 + tx;
        float v = tile[tx][ty + i * 8];
        size_t o = (size_t)n * Kp + k;
        unsigned short h = f2bf_rne(v);
        H[o] = h;
        L[o] = f2bf_rne(v - bf2f(h));
    }
}

__global__ __launch_bounds__(256) void prep_all_kernel(
    const float* __restrict__ W0, unsigned short* __restrict__ Bt0h, unsigned short* __restrict__ Bt0l,
    const float* __restrict__ W2, unsigned short* __restrict__ Bt2h, unsigned short* __restrict__ Bt2l,
    const float* __restrict__ W3, unsigned short* __restrict__ Bt3h, unsigned short* __restrict__ Bt3l,
    const float* __restrict__ W1, unsigned short* __restrict__ W1h, unsigned short* __restrict__ W1l,
    const float* __restrict__ X, unsigned short* __restrict__ Ah, unsigned short* __restrict__ Al,
    const float* __restrict__ b1, const float* __restrict__ b2, float* __restrict__ b12,
    const float* __restrict__ b3, float* __restrict__ b3p,
    const float* __restrict__ wEnc, const float* __restrict__ wDec, float* __restrict__ G)
{
    const int bid = blockIdx.x;
    const int tid = threadIdx.x;
    if (bid < 1024) {
        tsplit_block(W0, Bt0h, Bt0l, 1000, 1024, 1024, bid & 31, bid >> 5, tid);
    } else if (bid < 3072) {
        int b = bid - 1024;
        tsplit_block(W2, Bt2h, Bt2l, 2048, 1024, 2048, b & 63, b >> 6, tid);
    } else if (bid < 4096) {
        int b = bid - 3072;
        tsplit_block(W3, Bt3h, Bt3l, 1024, 1000, 1024, b & 31, b >> 5, tid);
    } else if (bid < 5120) {
        int r = bid - 4096;
        for (int c = tid; c < 2048; c += 256) {
            float v = W1[(size_t)r * 2048 + c];
            unsigned short h = f2bf_rne(v);
            size_t o = (size_t)r * 2048 + c;
            W1h[o] = h;
            W1l[o] = f2bf_rne(v - bf2f(h));
        }
    } else if (bid < 9216) {
        int r = bid - 5120;
        for (int c = tid; c < 1024; c += 256) {
            float v = (c < 1000) ? X[(size_t)r * 1000 + c] : 0.f;
            unsigned short h = f2bf_rne(v);
            size_t o = (size_t)r * 1024 + c;
            Ah[o] = h;
            Al[o] = f2bf_rne(v - bf2f(h));
        }
    } else if (bid < 9232) {
        __shared__ float red[4][64];
        const int tx = tid & 63, ty = tid >> 6;
        const int n = (bid - 9216) * 64 + tx;
        float s = 0.f;
        for (int j = ty * 512; j < (ty + 1) * 512; ++j)
            s += b1[j] * W2[(size_t)j * 1024 + n];
        red[ty][tx] = s;
        __syncthreads();
        if (ty == 0) b12[n] = red[0][tx] + red[1][tx] + red[2][tx] + red[3][tx] + b2[n];
    } else if (bid < 9236) {
        int i = (bid - 9232) * 256 + tid;
        b3p[i] = (i < 1000) ? b3[i] : 0.f;
    } else {
        int g = tid;
        if (g < 60) {
            const float* w = (g < 30) ? (wEnc + g * 3) : (wDec + (g - 30) * 3);
            float* o = G + ((g < 30) ? g : (g - 30 + 64)) * 8;
            float phi = w[0], th = w[1], om = w[2];
            float ch = cosf(0.5f * th), sh = sinf(0.5f * th);
            float ap = 0.5f * (phi + om), am = 0.5f * (phi - om);
            float cap = cosf(ap), sap = sinf(ap);
            float cam = cosf(am), sam = sinf(am);
            o[0] =  cap * ch; o[1] = -sap * ch;
            o[2] = -cam * sh; o[3] = -sam * sh;
            o[4] =  cam * sh; o[5] = -sam * sh;
            o[6] =  cap * ch; o[7] =  sap * ch;
        }
    }
}

// tsplit over the sum of 8 split-K partials: P = 8 x [1024][1024] fp32.
__global__ __launch_bounds__(256) void tsplit8_kernel(
    const float* __restrict__ P, unsigned short* __restrict__ H, unsigned short* __restrict__ L)
{
    __shared__ float tile[32][33];
    const int tid = threadIdx.x;
    const int tx = tid & 31, ty = tid >> 5;
    const int k0 = blockIdx.x * 32, n0 = blockIdx.y * 32;
    #pragma unroll
    for (int i = 0; i < 4; ++i) {
        int k = k0 + ty + i * 8, n = n0 + tx;
        size_t o = (size_t)k * 1024 + n;
        float s = 0.f;
        #pragma unroll
        for (int zz = 0; zz < 8; ++zz) s += P[o + ((size_t)zz << 20)];
        tile[ty + i * 8][tx] = s;
    }
    __syncthreads();
    #pragma unroll
    for (int i = 0; i < 4; ++i) {
        int n = n0 + ty + i * 8, k = k0 + tx;
        float v = tile[tx][ty + i * 8];
        size_t o = (size_t)n * 1024 + k;
        unsigned short h = f2bf_rne(v);
        H[o] = h;
        L[o] = f2bf_rne(v - bf2f(h));
    }
}

// ----------------- register-resident quantum circuit -----------------------
template<int GATE, int Q>
__device__ __forceinline__ void apply_rot(float (&xr)[16], float (&xi)[16],
                                          const float (&tbl)[8], int lane)
{
    float are = lane_bcast(tbl[0], GATE), aim = lane_bcast(tbl[1], GATE);
    float bre = lane_bcast(tbl[2], GATE), bim = lane_bcast(tbl[3], GATE);
    float cre = lane_bcast(tbl[4], GATE), cim = lane_bcast(tbl[5], GATE);
    float dre = lane_bcast(tbl[6], GATE), dim_ = lane_bcast(tbl[7], GATE);
    constexpr int S = 1 << (9 - Q);
    if constexpr (S < 16) {
        #pragma unroll
        for (int p = 0; p < 8; ++p) {
            int r0 = (p / S) * (2 * S) + (p % S);
            int r1 = r0 + S;
            float x0r = xr[r0], x0i = xi[r0], x1r = xr[r1], x1i = xi[r1];
            xr[r0] = are * x0r - aim * x0i + bre * x1r - bim * x1i;
            xi[r0] = are * x0i + aim * x0r + bre * x1i + bim * x1r;
            xr[r1] = cre * x0r - cim * x0i + dre * x1r - dim_ * x1i;
            xi[r1] = cre * x0i + cim * x0r + dre * x1i + dim_ * x1r;
        }
    } else {
        constexpr int M = S >> 4;
        bool bit = (lane & M) != 0;
        float pre = bit ? dre : are, pim = bit ? dim_ : aim;
        float qre = bit ? cre : bre, qim = bit ? cim : bim;
        #pragma unroll
        for (int r = 0; r < 16; ++r) {
            float ore = lane_xor<M>(xr[r]);
            float oim = lane_xor<M>(xi[r]);
            float nr = pre * xr[r] - pim * xi[r] + qre * ore - qim * oim;
            float ni = pre * xi[r] + pim * xr[r] + qre * oim + qim * ore;
            xr[r] = nr; xi[r] = ni;
        }
    }
}

template<int C, int T>
__device__ __forceinline__ void apply_cnot(float (&xr)[16], float (&xi)[16], int lane)
{
    constexpr int SC = 1 << (9 - C), ST = 1 << (9 - T);
    if constexpr (SC < 16 && ST < 16) {
        #pragma unroll
        for (int r = 0; r < 16; ++r) {
            if ((r & SC) && !(r & ST)) {
                int j = r | ST;
                float t;
                t = xr[r]; xr[r] = xr[j]; xr[j] = t;
                t = xi[r]; xi[r] = xi[j]; xi[j] = t;
            }
        }
    } else if constexpr (SC < 16) {
        constexpr int MT = ST >> 4;
        #pragma unroll
        for (int r = 0; r < 16; ++r) {
            if (r & SC) {
                xr[r] = lane_xor<MT>(xr[r]);
                xi[r] = lane_xor<MT>(xi[r]);
            }
        }
    } else if constexpr (ST < 16) {
        constexpr int MC = SC >> 4;
        bool bit = (lane & MC) != 0;
        #pragma unroll
        for (int r = 0; r < 16; ++r) {
            if (!(r & ST)) {
                int j = r | ST;
                float a0 = xr[r], a1 = xr[j];
                xr[r] = bit ? a1 : a0;  xr[j] = bit ? a0 : a1;
                float b0 = xi[r], b1 = xi[j];
                xi[r] = bit ? b1 : b0;  xi[j] = bit ? b0 : b1;
            }
        }
    } else {
        constexpr int MC = SC >> 4, MT = ST >> 4;
        bool bit = (lane & MC) != 0;
        #pragma unroll
        for (int r = 0; r < 16; ++r) {
            float o = lane_xor<MT>(xr[r]);
            xr[r] = bit ? o : xr[r];
            float oi = lane_xor<MT>(xi[r]);
            xi[r] = bit ? oi : xi[r];
        }
    }
}

template<int L, int Q>
__device__ __forceinline__ void rots(float (&xr)[16], float (&xi)[16],
                                     const float (&tbl)[8], int lane) {
    apply_rot<L * 10 + Q, Q>(xr, xi, tbl, lane);
    if constexpr (Q < 9) rots<L, Q + 1>(xr, xi, tbl, lane);
}
template<int L, int Q>
__device__ __forceinline__ void cnots(float (&xr)[16], float (&xi)[16], int lane) {
    constexpr int R = (L % 9) + 1;
    apply_cnot<Q, (Q + R) % 10>(xr, xi, lane);
    if constexpr (Q < 9) cnots<L, Q + 1>(xr, xi, lane);
}

__global__ __launch_bounds__(256, 4) void circuit_reg_kernel(
    const float* __restrict__ X0, const float* __restrict__ X1,
    unsigned short* __restrict__ Ph, unsigned short* __restrict__ Pl,
    const float* __restrict__ G)
{
    const int lane = threadIdx.x & 63;
    const int item = blockIdx.x * 4 + (threadIdx.x >> 6);
    const size_t base = (size_t)item * 1024 + lane * 16;

    float tbl[8];
    {
        const float4* gp = (const float4*)(G + lane * 8);
        float4 t0 = gp[0], t1 = gp[1];
        tbl[0] = t0.x; tbl[1] = t0.y; tbl[2] = t0.z; tbl[3] = t0.w;
        tbl[4] = t1.x; tbl[5] = t1.y; tbl[6] = t1.z; tbl[7] = t1.w;
    }

    float xr[16], xi[16];
    const float4* xb0 = (const float4*)(X0 + base);
    const float4* xb1 = (const float4*)(X1 + base);
    #pragma unroll
    for (int v = 0; v < 4; ++v) {
        float4 f = xb0[v], g = xb1[v];
        xr[v * 4 + 0] = f.x + g.x; xr[v * 4 + 1] = f.y + g.y;
        xr[v * 4 + 2] = f.z + g.z; xr[v * 4 + 3] = f.w + g.w;
    }
    #pragma unroll
    for (int r = 0; r < 16; ++r) xi[r] = 0.f;

    float nrm = 0.f;
    #pragma unroll
    for (int r = 0; r < 16; ++r) nrm += xr[r] * xr[r];
    nrm += lane_xor<1>(nrm);
    nrm += lane_xor<2>(nrm);
    nrm += lane_xor<4>(nrm);
    nrm += lane_xor<8>(nrm);
    nrm += lane_xor<16>(nrm);
    nrm += lane_xor<32>(nrm);
    float inv = 1.0f / sqrtf(nrm);
    #pragma unroll
    for (int r = 0; r < 16; ++r) xr[r] *= inv;

    rots<0, 0>(xr, xi, tbl, lane);  cnots<0, 0>(xr, xi, lane);
    rots<1, 0>(xr, xi, tbl, lane);  cnots<1, 0>(xr, xi, lane);
    rots<2, 0>(xr, xi, tbl, lane);  cnots<2, 0>(xr, xi, lane);

    u16x8 h[2], lo[2];
    #pragma unroll
    for (int r = 0; r < 16; ++r) {
        float p = xr[r] * xr[r] + xi[r] * xi[r];
        unsigned short hh = f2bf_rne(p);
        h[r >> 3][r & 7] = hh;
        lo[r >> 3][r & 7] = f2bf_rne(p - bf2f(hh));
    }
    *(u16x8*)(Ph + base) = h[0];
    *(u16x8*)(Ph + base + 8) = h[1];
    *(u16x8*)(Pl + base) = lo[0];
    *(u16x8*)(Pl + base + 8) = lo[1];
}

// --------------- abs + row-normalize (2 partials, single pass) -------------
__global__ __launch_bounds__(256) void absnorm_kernel(
    const float* __restrict__ P, size_t ZS, float* __restrict__ out, int N)
{
    __shared__ float red[4];
    const int row = blockIdx.x;
    const int tid = threadIdx.x;
    const size_t rb = (size_t)row * 1024 + tid * 4;

    float4 a = *(const float4*)(P + rb);
    float4 b = *(const float4*)(P + ZS + rb);
    float x[4] = { a.x + b.x, a.y + b.y, a.z + b.z, a.w + b.w };

    const int c0 = tid * 4;
    float s = 0.f;
    #pragma unroll
    for (int j = 0; j < 4; ++j) if (c0 + j < N) s += fabsf(x[j]);
    #pragma unroll
    for (int off = 32; off > 0; off >>= 1) s += __shfl_down(s, off);
    if ((tid & 63) == 0) red[tid >> 6] = s;
    __syncthreads();
    float inv = 1.0f / (red[0] + red[1] + red[2] + red[3]);
    #pragma unroll
    for (int j = 0; j < 4; ++j)
        if (c0 + j < N) out[(size_t)row * N + c0 + j] = fabsf(x[j]) * inv;
}

// ---------------------------------------------------------------------------
extern "C" void kernel_launch(void* const* d_in, const int* in_sizes, int n_in,
                              void* d_out, int out_size, void* d_ws, size_t ws_size,
                              hipStream_t stream)
{
    const float* inputs = (const float*)d_in[0];
    const float* wEnc   = (const float*)d_in[1];
    const float* wDec   = (const float*)d_in[2];
    const float* W0     = (const float*)d_in[3];
    const float* b0     = (const float*)d_in[4];
    const float* W1     = (const float*)d_in[5];
    const float* b1     = (const float*)d_in[6];
    const float* W2     = (const float*)d_in[7];
    const float* b2     = (const float*)d_in[8];
    const float* W3     = (const float*)d_in[9];
    const float* b3     = (const float*)d_in[10];
    float* out = (float*)d_out;

    char* w = (char*)d_ws;
    auto alloc = [&](size_t bytes) { char* p = w; w += (bytes + 255) & ~(size_t)255; return p; };

    unsigned short* Bt0h  = (unsigned short*)alloc((size_t)1024 * 1024 * 2);
    unsigned short* Bt0l  = (unsigned short*)alloc((size_t)1024 * 1024 * 2);
    unsigned short* Bt2h  = (unsigned short*)alloc((size_t)1024 * 2048 * 2);
    unsigned short* Bt2l  = (unsigned short*)alloc((size_t)1024 * 2048 * 2);
    unsigned short* Bt3h  = (unsigned short*)alloc((size_t)1024 * 1024 * 2);
    unsigned short* Bt3l  = (unsigned short*)alloc((size_t)1024 * 1024 * 2);
    unsigned short* Bt12h = (unsigned short*)alloc((size_t)1024 * 1024 * 2);
    unsigned short* Bt12l = (unsigned short*)alloc((size_t)1024 * 1024 * 2);
    unsigned short* W1h   = (unsigned short*)alloc((size_t)1024 * 2048 * 2);
    unsigned short* W1l   = (unsigned short*)alloc((size_t)1024 * 2048 * 2);
    float*          b3p   = (float*)alloc(1024 * 4);
    float*          b12   = (float*)alloc(1024 * 4);
    float*          G     = (float*)alloc(2 * 512 * 4);   // enc @ G, dec @ G+512
    unsigned short* Ah    = (unsigned short*)alloc((size_t)B_SZ * 1024 * 2);
    unsigned short* Al    = (unsigned short*)alloc((size_t)B_SZ * 1024 * 2);
    unsigned short* ph    = (unsigned short*)alloc((size_t)B_SZ * 1024 * 2);
    unsigned short* pl    = (unsigned short*)alloc((size_t)B_SZ * 1024 * 2);
    float*          P     = (float*)alloc((size_t)2 * B_SZ * 1024 * 4);  // split-K partials
    float* P12 = P;                 // 8 x [1024x1024] fp32 (32 MB) aliased; dead before G0
    const size_t ZS = (size_t)B_SZ * 1024;

    dim3 blk256(256);

    // ---- per-call prep: ONE dispatch ----
    prep_all_kernel<<<9237, blk256, 0, stream>>>(
        W0, Bt0h, Bt0l, W2, Bt2h, Bt2l, W3, Bt3h, Bt3l, W1, W1h, W1l,
        inputs, Ah, Al, b1, b2, b12, b3, b3p, wEnc, wDec, G);

    // ---- W12 = W1 @ W2 (split-K=8) -> transpose+split -> Bt12 ----
    gemm3_mfma<<<dim3(8, 8, 8), 512, 0, stream>>>(
        W1h, W1l, Bt2h, Bt2l, nullptr, P12, 2048, 1024, 256, (size_t)1 << 20);
    tsplit8_kernel<<<dim3(32, 32), blk256, 0, stream>>>(P12, Bt12h, Bt12l);

    // ---- pipeline (batch GEMMs split-K=2) ----
    gemm3_mfma<<<dim3(8, 32, 2), 512, 0, stream>>>(
        Ah, Al, Bt0h, Bt0l, b0, P, 1024, 1024, 512, ZS);
    circuit_reg_kernel<<<B_SZ / 4, blk256, 0, stream>>>(P, P + ZS, ph, pl, G);
    gemm3_mfma<<<dim3(8, 32, 2), 512, 0, stream>>>(
        ph, pl, Bt12h, Bt12l, b12, P, 1024, 1024, 512, ZS);
    circuit_reg_kernel<<<B_SZ / 4, blk256, 0, stream>>>(P, P + ZS, ph, pl, G + 512);
    gemm3_mfma<<<dim3(8, 32, 2), 512, 0, stream>>>(
        ph, pl, Bt3h, Bt3l, b3p, P, 1024, 1024, 512, ZS);
    absnorm_kernel<<<B_SZ, blk256, 0, stream>>>(P, ZS, out, 1000);
}

// Round 10
// 403.428 us; speedup vs baseline: 1.5141x; 1.0104x over previous
//
#include <hip/hip_runtime.h>
#include <math.h>

// ---------------------------------------------------------------------------
// QuantumAutoEncoder. Round 10: circuit split 2 waves per item (8 regs/lane,
// amp = (half<<9)|(lane<<3)|reg) -> 8192 waves = 8 waves/SIMD (was 4).
// Wire 0 = "wave bit": Rot + target-0 CNOT exchange via LDS (barrier-paired);
// control-0 CNOT is a wave-uniform local flip. GEMMs/prep: R9 verbatim
// (dbuf LDS + vmcnt(4) carry-across-barrier, split-K=2, W12 fusion).
// ---------------------------------------------------------------------------

#define B_SZ 4096
#define EMB 1024
#define NQ 10
#define NL 3

typedef __bf16 bf16x8 __attribute__((ext_vector_type(8)));
typedef float f32x4 __attribute__((ext_vector_type(4)));
typedef unsigned short u16x8 __attribute__((ext_vector_type(8)));

__device__ __forceinline__ unsigned short f2bf_rne(float f) {
    unsigned int u = __float_as_uint(f);
    u += 0x7FFFu + ((u >> 16) & 1u);
    return (unsigned short)(u >> 16);
}
__device__ __forceinline__ float bf2f(unsigned short h) {
    return __uint_as_float(((unsigned int)h) << 16);
}
__device__ __forceinline__ float lane_bcast(float v, int l) {
    return __uint_as_float(__builtin_amdgcn_readlane(__float_as_uint(v), l));
}

template<int M>
__device__ __forceinline__ float lane_xor(float v) {
    if constexpr (M == 1)
        return __uint_as_float(__builtin_amdgcn_mov_dpp(__float_as_uint(v), 0xB1, 0xF, 0xF, true));
    else if constexpr (M == 2)
        return __uint_as_float(__builtin_amdgcn_mov_dpp(__float_as_uint(v), 0x4E, 0xF, 0xF, true));
    else if constexpr (M == 8)
        return __uint_as_float(__builtin_amdgcn_mov_dpp(__float_as_uint(v), 0x128, 0xF, 0xF, true));
    else if constexpr (M == 4)
        return __uint_as_float(__builtin_amdgcn_ds_swizzle(__float_as_uint(v), 0x101F));
    else if constexpr (M == 16)
        return __uint_as_float(__builtin_amdgcn_ds_swizzle(__float_as_uint(v), 0x401F));
    else
        return __shfl_xor(v, 32, 64);
}

__device__ __forceinline__ void gll16(const void* g, void* l) {
    __builtin_amdgcn_global_load_lds(
        (const __attribute__((address_space(1))) void*)g,
        (__attribute__((address_space(3))) void*)l, 16, 0, 0);
}

// waitcnt imm (gfx9): vmcnt[3:0], expcnt[6:4]=7 (none), lgkmcnt[11:8]=0xF (none)
#define WAITCNT_VM(N) __builtin_amdgcn_s_waitcnt(0x0F70 | (N))

// ---------------- MFMA GEMM (bf16x3), double-buffered LDS ------------------
#define GBM 128
#define GBN 128
#define GBK 32

__global__ __launch_bounds__(512) void gemm3_mfma(
    const unsigned short* __restrict__ Ah, const unsigned short* __restrict__ Al,
    const unsigned short* __restrict__ Bh, const unsigned short* __restrict__ Bl,
    const float* __restrict__ bias, float* __restrict__ C,
    int Kp, int Np, int Ksplit, size_t zStride)
{
    __shared__ __align__(16) char lds[65536];   // 2 x 32KB buffers

    const int tid = threadIdx.x;
    const int lane = tid & 63;
    const int wv = tid >> 6;
    const int wm = wv >> 1;
    const int wn = wv & 1;
    const int blockRow = blockIdx.y * GBM;
    const int blockCol = blockIdx.x * GBN;
    const int z = blockIdx.z;

    const int srow = tid >> 2;
    const int skel = (tid & 3) * 8;
    const size_t aOff = ((size_t)(blockRow + srow) * Kp + skel + (size_t)z * Ksplit) * 2;
    const size_t bOff = ((size_t)(blockCol + srow) * Kp + skel + (size_t)z * Ksplit) * 2;
    const char* aHp = (const char*)Ah + aOff;
    const char* aLp = (const char*)Al + aOff;
    const char* bHp = (const char*)Bh + bOff;
    const char* bLp = (const char*)Bl + bOff;
    const int stageOff = wv * 1024;

    f32x4 acc[2][4];
    #pragma unroll
    for (int i = 0; i < 2; ++i)
        #pragma unroll
        for (int j = 0; j < 4; ++j)
            #pragma unroll
            for (int r = 0; r < 4; ++r) acc[i][j][r] = 0.f;

    const int kq = (lane >> 4) * 16;
    int aFragOff[2], bFragOff[4];
    #pragma unroll
    for (int i = 0; i < 2; ++i) aFragOff[i] = (wm * 32 + i * 16 + (lane & 15)) * 64 + kq;
    #pragma unroll
    for (int j = 0; j < 4; ++j) bFragOff[j] = (wn * 64 + j * 16 + (lane & 15)) * 64 + kq;

    auto stage = [&](int s, int buf) {
        char* base = lds + buf * 32768;
        const size_t kb = (size_t)s * GBK * 2;
        gll16(aHp + kb, base + stageOff);
        gll16(aLp + kb, base + 8192 + stageOff);
        gll16(bHp + kb, base + 16384 + stageOff);
        gll16(bLp + kb, base + 24576 + stageOff);
    };

    const int nsteps = Ksplit / GBK;
    stage(0, 0);
    for (int s = 0; s < nsteps; ++s) {
        const int buf = s & 1;
        if (s + 1 < nsteps) {
            stage(s + 1, buf ^ 1);
            WAITCNT_VM(4);          // wait for this tile; next tile stays in flight
        } else {
            WAITCNT_VM(0);
        }
        __builtin_amdgcn_s_barrier();

        char* base = lds + buf * 32768;
        bf16x8 ah[2], al[2], bh[4], bl[4];
        #pragma unroll
        for (int i = 0; i < 2; ++i) {
            ah[i] = *(const bf16x8*)(base + aFragOff[i]);
            al[i] = *(const bf16x8*)(base + 8192 + aFragOff[i]);
        }
        #pragma unroll
        for (int j = 0; j < 4; ++j) {
            bh[j] = *(const bf16x8*)(base + 16384 + bFragOff[j]);
            bl[j] = *(const bf16x8*)(base + 24576 + bFragOff[j]);
        }
        #pragma unroll
        for (int j = 0; j < 4; ++j)
            #pragma unroll
            for (int i = 0; i < 2; ++i) {
                acc[i][j] = __builtin_amdgcn_mfma_f32_16x16x32_bf16(al[i], bh[j], acc[i][j], 0, 0, 0);
                acc[i][j] = __builtin_amdgcn_mfma_f32_16x16x32_bf16(ah[i], bl[j], acc[i][j], 0, 0, 0);
                acc[i][j] = __builtin_amdgcn_mfma_f32_16x16x32_bf16(ah[i], bh[j], acc[i][j], 0, 0, 0);
            }
        __syncthreads();            // protect buf^1 region before restaging it
    }

    float* Cz = C + (size_t)z * zStride;
    const bool addB = (z == 0) && (bias != nullptr);
    const int rquad = (lane >> 4) * 4;
    const int cidx = lane & 15;
    #pragma unroll
    for (int i = 0; i < 2; ++i)
        #pragma unroll
        for (int j = 0; j < 4; ++j) {
            #pragma unroll
            for (int r = 0; r < 4; ++r) {
                int row = blockRow + wm * 32 + i * 16 + rquad + r;
                int col = blockCol + wn * 64 + j * 16 + cidx;
                float v = acc[i][j][r];
                if (addB) v += bias[col];
                Cz[(size_t)row * Np + col] = v;
            }
        }
}

// --------------------------- unified prep kernel ---------------------------
__device__ __forceinline__ void tsplit_block(
    const float* __restrict__ W, unsigned short* __restrict__ H, unsigned short* __restrict__ L,
    int K, int N, int Kp, int bx, int by, int tid)
{
    __shared__ float tile[32][33];
    const int tx = tid & 31, ty = tid >> 5;
    const int k0 = bx * 32, n0 = by * 32;
    #pragma unroll
    for (int i = 0; i < 4; ++i) {
        int k = k0 + ty + i * 8, n = n0 + tx;
        tile[ty + i * 8][tx] = (k < K && n < N) ? W[(size_t)k * N + n] : 0.f;
    }
    __syncthreads();
    #pragma unroll
    for (int i = 0; i < 4; ++i) {
        int n = n0 + ty + i * 8, k = k0 + tx;
        float v = tile[tx][ty + i * 8];
        size_t o = (size_t)n * Kp + k;
        unsigned short h = f2bf_rne(v);
        H[o] = h;
        L[o] = f2bf_rne(v - bf2f(h));
    }
}

__global__ __launch_bounds__(256) void prep_all_kernel(
    const float* __restrict__ W0, unsigned short* __restrict__ Bt0h, unsigned short* __restrict__ Bt0l,
    const float* __restrict__ W2, unsigned short* __restrict__ Bt2h, unsigned short* __restrict__ Bt2l,
    const float* __restrict__ W3, unsigned short* __restrict__ Bt3h, unsigned short* __restrict__ Bt3l,
    const float* __restrict__ W1, unsigned short* __restrict__ W1h, unsigned short* __restrict__ W1l,
    const float* __restrict__ X, unsigned short* __restrict__ Ah, unsigned short* __restrict__ Al,
    const float* __restrict__ b1, const float* __restrict__ b2, float* __restrict__ b12,
    const float* __restrict__ b3, float* __restrict__ b3p,
    const float* __restrict__ wEnc, const float* __restrict__ wDec, float* __restrict__ G)
{
    const int bid = blockIdx.x;
    const int tid = threadIdx.x;
    if (bid < 1024) {
        tsplit_block(W0, Bt0h, Bt0l, 1000, 1024, 1024, bid & 31, bid >> 5, tid);
    } else if (bid < 3072) {
        int b = bid - 1024;
        tsplit_block(W2, Bt2h, Bt2l, 2048, 1024, 2048, b & 63, b >> 6, tid);
    } else if (bid < 4096) {
        int b = bid - 3072;
        tsplit_block(W3, Bt3h, Bt3l, 1024, 1000, 1024, b & 31, b >> 5, tid);
    } else if (bid < 5120) {
        int r = bid - 4096;
        for (int c = tid; c < 2048; c += 256) {
            float v = W1[(size_t)r * 2048 + c];
            unsigned short h = f2bf_rne(v);
            size_t o = (size_t)r * 2048 + c;
            W1h[o] = h;
            W1l[o] = f2bf_rne(v - bf2f(h));
        }
    } else if (bid < 9216) {
        int r = bid - 5120;
        for (int c = tid; c < 1024; c += 256) {
            float v = (c < 1000) ? X[(size_t)r * 1000 + c] : 0.f;
            unsigned short h = f2bf_rne(v);
            size_t o = (size_t)r * 1024 + c;
            Ah[o] = h;
            Al[o] = f2bf_rne(v - bf2f(h));
        }
    } else if (bid < 9232) {
        __shared__ float red[4][64];
        const int tx = tid & 63, ty = tid >> 6;
        const int n = (bid - 9216) * 64 + tx;
        float s = 0.f;
        for (int j = ty * 512; j < (ty + 1) * 512; ++j)
            s += b1[j] * W2[(size_t)j * 1024 + n];
        red[ty][tx] = s;
        __syncthreads();
        if (ty == 0) b12[n] = red[0][tx] + red[1][tx] + red[2][tx] + red[3][tx] + b2[n];
    } else if (bid < 9236) {
        int i = (bid - 9232) * 256 + tid;
        b3p[i] = (i < 1000) ? b3[i] : 0.f;
    } else {
        int g = tid;
        if (g < 60) {
            const float* w = (g < 30) ? (wEnc + g * 3) : (wDec + (g - 30) * 3);
            float* o = G + ((g < 30) ? g : (g - 30 + 64)) * 8;
            float phi = w[0], th = w[1], om = w[2];
            float ch = cosf(0.5f * th), sh = sinf(0.5f * th);
            float ap = 0.5f * (phi + om), am = 0.5f * (phi - om);
            float cap = cosf(ap), sap = sinf(ap);
            float cam = cosf(am), sam = sinf(am);
            o[0] =  cap * ch; o[1] = -sap * ch;
            o[2] = -cam * sh; o[3] = -sam * sh;
            o[4] =  cam * sh; o[5] = -sam * sh;
            o[6] =  cap * ch; o[7] =  sap * ch;
        }
    }
}

// tsplit over the sum of 8 split-K partials: P = 8 x [1024][1024] fp32.
__global__ __launch_bounds__(256) void tsplit8_kernel(
    const float* __restrict__ P, unsigned short* __restrict__ H, unsigned short* __restrict__ L)
{
    __shared__ float tile[32][33];
    const int tid = threadIdx.x;
    const int tx = tid & 31, ty = tid >> 5;
    const int k0 = blockIdx.x * 32, n0 = blockIdx.y * 32;
    #pragma unroll
    for (int i = 0; i < 4; ++i) {
        int k = k0 + ty + i * 8, n = n0 + tx;
        size_t o = (size_t)k * 1024 + n;
        float s = 0.f;
        #pragma unroll
        for (int zz = 0; zz < 8; ++zz) s += P[o + ((size_t)zz << 20)];
        tile[ty + i * 8][tx] = s;
    }
    __syncthreads();
    #pragma unroll
    for (int i = 0; i < 4; ++i) {
        int n = n0 + ty + i * 8, k = k0 + tx;
        float v = tile[tx][ty + i * 8];
        size_t o = (size_t)n * 1024 + k;
        unsigned short h = f2bf_rne(v);
        H[o] = h;
        L[o] = f2bf_rne(v - bf2f(h));
    }
}

// ------------- register-resident quantum circuit, 2 waves/item -------------
// amp idx = (half<<9) | (lane<<3) | reg. Wire q stride S = 1<<(9-q):
//   S<8   -> register bit
//   8..256-> lane bit, mask M = S>>3
//   512   -> wave bit (half): exchange via LDS (barrier-paired)

template<int GATE, int Q>
__device__ __forceinline__ void apply_rot2(float (&xr)[8], float (&xi)[8],
    const float (&tbl)[8], int lane, int half, float2 (&xc)[2][8][64])
{
    float are = lane_bcast(tbl[0], GATE), aim = lane_bcast(tbl[1], GATE);
    float bre = lane_bcast(tbl[2], GATE), bim = lane_bcast(tbl[3], GATE);
    float cre = lane_bcast(tbl[4], GATE), cim = lane_bcast(tbl[5], GATE);
    float dre = lane_bcast(tbl[6], GATE), dim_ = lane_bcast(tbl[7], GATE);
    constexpr int S = 1 << (9 - Q);
    if constexpr (S < 8) {
        #pragma unroll
        for (int p = 0; p < 4; ++p) {
            int r0 = (p / S) * (2 * S) + (p % S);
            int r1 = r0 + S;
            float x0r = xr[r0], x0i = xi[r0], x1r = xr[r1], x1i = xi[r1];
            xr[r0] = are * x0r - aim * x0i + bre * x1r - bim * x1i;
            xi[r0] = are * x0i + aim * x0r + bre * x1i + bim * x1r;
            xr[r1] = cre * x0r - cim * x0i + dre * x1r - dim_ * x1i;
            xi[r1] = cre * x0i + cim * x0r + dre * x1i + dim_ * x1r;
        }
    } else if constexpr (S < 512) {
        constexpr int M = S >> 3;
        bool bit = (lane & M) != 0;
        float pre = bit ? dre : are, pim = bit ? dim_ : aim;
        float qre = bit ? cre : bre, qim = bit ? cim : bim;
        #pragma unroll
        for (int r = 0; r < 8; ++r) {
            float ore = lane_xor<M>(xr[r]);
            float oim = lane_xor<M>(xi[r]);
            float nr = pre * xr[r] - pim * xi[r] + qre * ore - qim * oim;
            float ni = pre * xi[r] + pim * xr[r] + qre * oim + qim * ore;
            xr[r] = nr; xi[r] = ni;
        }
    } else {
        // wave bit: exchange full state with partner wave via LDS
        #pragma unroll
        for (int r = 0; r < 8; ++r) xc[half][r][lane] = make_float2(xr[r], xi[r]);
        __syncthreads();
        float pre = half ? dre : are, pim = half ? dim_ : aim;
        float qre = half ? cre : bre, qim = half ? cim : bim;
        #pragma unroll
        for (int r = 0; r < 8; ++r) {
            float2 o = xc[half ^ 1][r][lane];
            float nr = pre * xr[r] - pim * xi[r] + qre * o.x - qim * o.y;
            float ni = pre * xi[r] + pim * xr[r] + qre * o.y + qim * o.x;
            xr[r] = nr; xi[r] = ni;
        }
        __syncthreads();
    }
}

template<int C, int T>
__device__ __forceinline__ void apply_cnot2(float (&xr)[8], float (&xi)[8],
    int lane, int half, float2 (&xc)[2][8][64])
{
    constexpr int SC = 1 << (9 - C), ST = 1 << (9 - T);
    if constexpr (SC >= 512) {
        // control = wave bit: half==1 waves apply X on target locally
        if (half) {                      // wave-uniform branch
            if constexpr (ST >= 8) {
                constexpr int MT = ST >> 3;
                #pragma unroll
                for (int r = 0; r < 8; ++r) {
                    xr[r] = lane_xor<MT>(xr[r]);
                    xi[r] = lane_xor<MT>(xi[r]);
                }
            } else {
                #pragma unroll
                for (int r = 0; r < 8; ++r) {
                    if (!(r & ST)) {
                        int j = r | ST;
                        float t;
                        t = xr[r]; xr[r] = xr[j]; xr[j] = t;
                        t = xi[r]; xi[r] = xi[j]; xi[j] = t;
                    }
                }
            }
        }
    } else if constexpr (ST >= 512) {
        // target = wave bit: amps with control bit=1 swap halves (LDS exchange)
        if constexpr (SC < 8) {
            #pragma unroll
            for (int r = 0; r < 8; ++r)
                if (r & SC) xc[half][r][lane] = make_float2(xr[r], xi[r]);
            __syncthreads();
            #pragma unroll
            for (int r = 0; r < 8; ++r)
                if (r & SC) {
                    float2 o = xc[half ^ 1][r][lane];
                    xr[r] = o.x; xi[r] = o.y;
                }
            __syncthreads();
        } else {
            constexpr int MC = SC >> 3;
            #pragma unroll
            for (int r = 0; r < 8; ++r) xc[half][r][lane] = make_float2(xr[r], xi[r]);
            __syncthreads();
            if (lane & MC) {
                #pragma unroll
                for (int r = 0; r < 8; ++r) {
                    float2 o = xc[half ^ 1][r][lane];
                    xr[r] = o.x; xi[r] = o.y;
                }
            }
            __syncthreads();
        }
    } else if constexpr (SC < 8 && ST < 8) {
        #pragma unroll
        for (int r = 0; r < 8; ++r) {
            if ((r & SC) && !(r & ST)) {
                int j = r | ST;
                float t;
                t = xr[r]; xr[r] = xr[j]; xr[j] = t;
                t = xi[r]; xi[r] = xi[j]; xi[j] = t;
            }
        }
    } else if constexpr (SC < 8) {
        // control reg bit, target lane bit
        constexpr int MT = ST >> 3;
        #pragma unroll
        for (int r = 0; r < 8; ++r) {
            if (r & SC) {
                xr[r] = lane_xor<MT>(xr[r]);
                xi[r] = lane_xor<MT>(xi[r]);
            }
        }
    } else if constexpr (ST < 8) {
        // control lane bit, target reg bit
        constexpr int MC = SC >> 3;
        bool bit = (lane & MC) != 0;
        #pragma unroll
        for (int r = 0; r < 8; ++r) {
            if (!(r & ST)) {
                int j = r | ST;
                float a0 = xr[r], a1 = xr[j];
                xr[r] = bit ? a1 : a0;  xr[j] = bit ? a0 : a1;
                float b0 = xi[r], b1 = xi[j];
                xi[r] = bit ? b1 : b0;  xi[j] = bit ? b0 : b1;
            }
        }
    } else {
        // both lane bits
        constexpr int MC = SC >> 3, MT = ST >> 3;
        bool bit = (lane & MC) != 0;
        #pragma unroll
        for (int r = 0; r < 8; ++r) {
            float o = lane_xor<MT>(xr[r]);
            xr[r] = bit ? o : xr[r];
            float oi = lane_xor<MT>(xi[r]);
            xi[r] = bit ? oi : xi[r];
        }
    }
}

template<int L, int Q>
__device__ __forceinline__ void rots2(float (&xr)[8], float (&xi)[8],
    const float (&tbl)[8], int lane, int half, float2 (&xc)[2][8][64]) {
    apply_rot2<L * 10 + Q, Q>(xr, xi, tbl, lane, half, xc);
    if constexpr (Q < 9) rots2<L, Q + 1>(xr, xi, tbl, lane, half, xc);
}
template<int L, int Q>
__device__ __forceinline__ void cnots2(float (&xr)[8], float (&xi)[8],
    int lane, int half, float2 (&xc)[2][8][64]) {
    constexpr int R = (L % 9) + 1;
    apply_cnot2<Q, (Q + R) % 10>(xr, xi, lane, half, xc);
    if constexpr (Q < 9) cnots2<L, Q + 1>(xr, xi, lane, half, xc);
}

// X = X0 + X1 (split-K partials) -> circuit -> hi/lo bf16 split probs.
// Grid 2048 x 256: block = 2 items x 2 waves.
__global__ __launch_bounds__(256, 6) void circuit2w_kernel(
    const float* __restrict__ X0, const float* __restrict__ X1,
    unsigned short* __restrict__ Ph, unsigned short* __restrict__ Pl,
    const float* __restrict__ G)
{
    __shared__ float2 xch[2][2][8][64];     // [item][half][reg][lane]
    __shared__ float nsum[2][2];

    const int lane = threadIdx.x & 63;
    const int wv = threadIdx.x >> 6;        // 0..3
    const int it = wv >> 1;                 // item within block
    const int half = wv & 1;                // amp bit 9 (wire 0)
    const int item = blockIdx.x * 2 + it;
    const size_t base = (size_t)item * 1024 + (size_t)half * 512 + lane * 8;

    float tbl[8];
    {
        const float4* gp = (const float4*)(G + lane * 8);
        float4 t0 = gp[0], t1 = gp[1];
        tbl[0] = t0.x; tbl[1] = t0.y; tbl[2] = t0.z; tbl[3] = t0.w;
        tbl[4] = t1.x; tbl[5] = t1.y; tbl[6] = t1.z; tbl[7] = t1.w;
    }

    float xr[8], xi[8];
    const float4* a0 = (const float4*)(X0 + base);
    const float4* a1 = (const float4*)(X1 + base);
    #pragma unroll
    for (int v = 0; v < 2; ++v) {
        float4 f = a0[v], g = a1[v];
        xr[v * 4 + 0] = f.x + g.x; xr[v * 4 + 1] = f.y + g.y;
        xr[v * 4 + 2] = f.z + g.z; xr[v * 4 + 3] = f.w + g.w;
    }
    #pragma unroll
    for (int r = 0; r < 8; ++r) xi[r] = 0.f;

    float s = 0.f;
    #pragma unroll
    for (int r = 0; r < 8; ++r) s += xr[r] * xr[r];
    s += lane_xor<1>(s);
    s += lane_xor<2>(s);
    s += lane_xor<4>(s);
    s += lane_xor<8>(s);
    s += lane_xor<16>(s);
    s += lane_xor<32>(s);
    if (lane == 0) nsum[it][half] = s;
    __syncthreads();
    float inv = 1.0f / sqrtf(nsum[it][0] + nsum[it][1]);
    #pragma unroll
    for (int r = 0; r < 8; ++r) xr[r] *= inv;

    rots2<0, 0>(xr, xi, tbl, lane, half, xch[it]);  cnots2<0, 0>(xr, xi, lane, half, xch[it]);
    rots2<1, 0>(xr, xi, tbl, lane, half, xch[it]);  cnots2<1, 0>(xr, xi, lane, half, xch[it]);
    rots2<2, 0>(xr, xi, tbl, lane, half, xch[it]);  cnots2<2, 0>(xr, xi, lane, half, xch[it]);

    u16x8 h, lo;
    #pragma unroll
    for (int r = 0; r < 8; ++r) {
        float p = xr[r] * xr[r] + xi[r] * xi[r];
        unsigned short hh = f2bf_rne(p);
        h[r] = hh;
        lo[r] = f2bf_rne(p - bf2f(hh));
    }
    *(u16x8*)(Ph + base) = h;
    *(u16x8*)(Pl + base) = lo;
}

// --------------- abs + row-normalize (2 partials, single pass) -------------
__global__ __launch_bounds__(256) void absnorm_kernel(
    const float* __restrict__ P, size_t ZS, float* __restrict__ out, int N)
{
    __shared__ float red[4];
    const int row = blockIdx.x;
    const int tid = threadIdx.x;
    const size_t rb = (size_t)row * 1024 + tid * 4;

    float4 a = *(const float4*)(P + rb);
    float4 b = *(const float4*)(P + ZS + rb);
    float x[4] = { a.x + b.x, a.y + b.y, a.z + b.z, a.w + b.w };

    const int c0 = tid * 4;
    float s = 0.f;
    #pragma unroll
    for (int j = 0; j < 4; ++j) if (c0 + j < N) s += fabsf(x[j]);
    #pragma unroll
    for (int off = 32; off > 0; off >>= 1) s += __shfl_down(s, off);
    if ((tid & 63) == 0) red[tid >> 6] = s;
    __syncthreads();
    float inv = 1.0f / (red[0] + red[1] + red[2] + red[3]);
    #pragma unroll
    for (int j = 0; j < 4; ++j)
        if (c0 + j < N) out[(size_t)row * N + c0 + j] = fabsf(x[j]) * inv;
}

// ---------------------------------------------------------------------------
extern "C" void kernel_launch(void* const* d_in, const int* in_sizes, int n_in,
                              void* d_out, int out_size, void* d_ws, size_t ws_size,
                              hipStream_t stream)
{
    const float* inputs = (const float*)d_in[0];
    const float* wEnc   = (const float*)d_in[1];
    const float* wDec   = (const float*)d_in[2];
    const float* W0     = (const float*)d_in[3];
    const float* b0     = (const float*)d_in[4];
    const float* W1     = (const float*)d_in[5];
    const float* b1     = (const float*)d_in[6];
    const float* W2     = (const float*)d_in[7];
    const float* b2     = (const float*)d_in[8];
    const float* W3     = (const float*)d_in[9];
    const float* b3     = (const float*)d_in[10];
    float* out = (float*)d_out;

    char* w = (char*)d_ws;
    auto alloc = [&](size_t bytes) { char* p = w; w += (bytes + 255) & ~(size_t)255; return p; };

    unsigned short* Bt0h  = (unsigned short*)alloc((size_t)1024 * 1024 * 2);
    unsigned short* Bt0l  = (unsigned short*)alloc((size_t)1024 * 1024 * 2);
    unsigned short* Bt2h  = (unsigned short*)alloc((size_t)1024 * 2048 * 2);
    unsigned short* Bt2l  = (unsigned short*)alloc((size_t)1024 * 2048 * 2);
    unsigned short* Bt3h  = (unsigned short*)alloc((size_t)1024 * 1024 * 2);
    unsigned short* Bt3l  = (unsigned short*)alloc((size_t)1024 * 1024 * 2);
    unsigned short* Bt12h = (unsigned short*)alloc((size_t)1024 * 1024 * 2);
    unsigned short* Bt12l = (unsigned short*)alloc((size_t)1024 * 1024 * 2);
    unsigned short* W1h   = (unsigned short*)alloc((size_t)1024 * 2048 * 2);
    unsigned short* W1l   = (unsigned short*)alloc((size_t)1024 * 2048 * 2);
    float*          b3p   = (float*)alloc(1024 * 4);
    float*          b12   = (float*)alloc(1024 * 4);
    float*          G     = (float*)alloc(2 * 512 * 4);   // enc @ G, dec @ G+512
    unsigned short* Ah    = (unsigned short*)alloc((size_t)B_SZ * 1024 * 2);
    unsigned short* Al    = (unsigned short*)alloc((size_t)B_SZ * 1024 * 2);
    unsigned short* ph    = (unsigned short*)alloc((size_t)B_SZ * 1024 * 2);
    unsigned short* pl    = (unsigned short*)alloc((size_t)B_SZ * 1024 * 2);
    float*          P     = (float*)alloc((size_t)2 * B_SZ * 1024 * 4);  // split-K partials
    float* P12 = P;                 // 8 x [1024x1024] fp32 (32 MB) aliased; dead before G0
    const size_t ZS = (size_t)B_SZ * 1024;

    dim3 blk256(256);

    // ---- per-call prep: ONE dispatch ----
    prep_all_kernel<<<9237, blk256, 0, stream>>>(
        W0, Bt0h, Bt0l, W2, Bt2h, Bt2l, W3, Bt3h, Bt3l, W1, W1h, W1l,
        inputs, Ah, Al, b1, b2, b12, b3, b3p, wEnc, wDec, G);

    // ---- W12 = W1 @ W2 (split-K=8) -> transpose+split -> Bt12 ----
    gemm3_mfma<<<dim3(8, 8, 8), 512, 0, stream>>>(
        W1h, W1l, Bt2h, Bt2l, nullptr, P12, 2048, 1024, 256, (size_t)1 << 20);
    tsplit8_kernel<<<dim3(32, 32), blk256, 0, stream>>>(P12, Bt12h, Bt12l);

    // ---- pipeline (batch GEMMs split-K=2) ----
    gemm3_mfma<<<dim3(8, 32, 2), 512, 0, stream>>>(
        Ah, Al, Bt0h, Bt0l, b0, P, 1024, 1024, 512, ZS);
    circuit2w_kernel<<<2048, blk256, 0, stream>>>(P, P + ZS, ph, pl, G);
    gemm3_mfma<<<dim3(8, 32, 2), 512, 0, stream>>>(
        ph, pl, Bt12h, Bt12l, b12, P, 1024, 1024, 512, ZS);
    circuit2w_kernel<<<2048, blk256, 0, stream>>>(P, P + ZS, ph, pl, G + 512);
    gemm3_mfma<<<dim3(8, 32, 2), 512, 0, stream>>>(
        ph, pl, Bt3h, Bt3l, b3p, P, 1024, 1024, 512, ZS);
    absnorm_kernel<<<B_SZ, blk256, 0, stream>>>(P, ZS, out, 1000);
}

// Round 11
// 371.320 us; speedup vs baseline: 1.6450x; 1.0865x over previous
//
#include <hip/hip_runtime.h>
#include <math.h>

// ---------------------------------------------------------------------------
// QuantumAutoEncoder. Round 11:
//  (a) circuit code-size shrink ~2.4x: layer loop NOT unrolled (runtime gate
//      index into readlane broadcasts), CNOTs 3-way branched -- attacks the
//      I$-streaming ceiling (circuit stuck ~55% VALU at any occupancy).
//  (b) dispatch fusion: W12-GEMM runs inside the GEMM0 dispatch (P12 now a
//      separate buffer), tsplit8 runs inside the circuit-enc dispatch.
//  (c) GEMM core: R9 verbatim (dbuf LDS + vmcnt(4) carry-across-barrier).
// ---------------------------------------------------------------------------

#define B_SZ 4096
#define EMB 1024
#define NQ 10
#define NL 3

typedef __bf16 bf16x8 __attribute__((ext_vector_type(8)));
typedef float f32x4 __attribute__((ext_vector_type(4)));
typedef unsigned short u16x8 __attribute__((ext_vector_type(8)));

__device__ __forceinline__ unsigned short f2bf_rne(float f) {
    unsigned int u = __float_as_uint(f);
    u += 0x7FFFu + ((u >> 16) & 1u);
    return (unsigned short)(u >> 16);
}
__device__ __forceinline__ float bf2f(unsigned short h) {
    return __uint_as_float(((unsigned int)h) << 16);
}
__device__ __forceinline__ float lane_bcast(float v, int l) {
    return __uint_as_float(__builtin_amdgcn_readlane(__float_as_uint(v), l));
}

template<int M>
__device__ __forceinline__ float lane_xor(float v) {
    if constexpr (M == 1)
        return __uint_as_float(__builtin_amdgcn_mov_dpp(__float_as_uint(v), 0xB1, 0xF, 0xF, true));
    else if constexpr (M == 2)
        return __uint_as_float(__builtin_amdgcn_mov_dpp(__float_as_uint(v), 0x4E, 0xF, 0xF, true));
    else if constexpr (M == 8)
        return __uint_as_float(__builtin_amdgcn_mov_dpp(__float_as_uint(v), 0x128, 0xF, 0xF, true));
    else if constexpr (M == 4)
        return __uint_as_float(__builtin_amdgcn_ds_swizzle(__float_as_uint(v), 0x101F));
    else if constexpr (M == 16)
        return __uint_as_float(__builtin_amdgcn_ds_swizzle(__float_as_uint(v), 0x401F));
    else
        return __shfl_xor(v, 32, 64);
}

__device__ __forceinline__ void gll16(const void* g, void* l) {
    __builtin_amdgcn_global_load_lds(
        (const __attribute__((address_space(1))) void*)g,
        (__attribute__((address_space(3))) void*)l, 16, 0, 0);
}

// waitcnt imm (gfx9): vmcnt[3:0], expcnt[6:4]=7 (none), lgkmcnt[11:8]=0xF (none)
#define WAITCNT_VM(N) __builtin_amdgcn_s_waitcnt(0x0F70 | (N))

// ---------------- MFMA GEMM body (bf16x3), double-buffered LDS -------------
#define GBM 128
#define GBN 128
#define GBK 32

__device__ __forceinline__ void gemm_body(
    const unsigned short* __restrict__ Ah, const unsigned short* __restrict__ Al,
    const unsigned short* __restrict__ Bh, const unsigned short* __restrict__ Bl,
    const float* __restrict__ bias, float* __restrict__ C,
    int Kp, int Np, int Ksplit, size_t zStride,
    int bx, int by, int bz, int tid, char* lds)
{
    const int lane = tid & 63;
    const int wv = tid >> 6;
    const int wm = wv >> 1;
    const int wn = wv & 1;
    const int blockRow = by * GBM;
    const int blockCol = bx * GBN;
    const int z = bz;

    const int srow = tid >> 2;
    const int skel = (tid & 3) * 8;
    const size_t aOff = ((size_t)(blockRow + srow) * Kp + skel + (size_t)z * Ksplit) * 2;
    const size_t bOff = ((size_t)(blockCol + srow) * Kp + skel + (size_t)z * Ksplit) * 2;
    const char* aHp = (const char*)Ah + aOff;
    const char* aLp = (const char*)Al + aOff;
    const char* bHp = (const char*)Bh + bOff;
    const char* bLp = (const char*)Bl + bOff;
    const int stageOff = wv * 1024;

    f32x4 acc[2][4];
    #pragma unroll
    for (int i = 0; i < 2; ++i)
        #pragma unroll
        for (int j = 0; j < 4; ++j)
            #pragma unroll
            for (int r = 0; r < 4; ++r) acc[i][j][r] = 0.f;

    const int kq = (lane >> 4) * 16;
    int aFragOff[2], bFragOff[4];
    #pragma unroll
    for (int i = 0; i < 2; ++i) aFragOff[i] = (wm * 32 + i * 16 + (lane & 15)) * 64 + kq;
    #pragma unroll
    for (int j = 0; j < 4; ++j) bFragOff[j] = (wn * 64 + j * 16 + (lane & 15)) * 64 + kq;

    auto stage = [&](int s, int buf) {
        char* base = lds + buf * 32768;
        const size_t kb = (size_t)s * GBK * 2;
        gll16(aHp + kb, base + stageOff);
        gll16(aLp + kb, base + 8192 + stageOff);
        gll16(bHp + kb, base + 16384 + stageOff);
        gll16(bLp + kb, base + 24576 + stageOff);
    };

    const int nsteps = Ksplit / GBK;
    stage(0, 0);
    for (int s = 0; s < nsteps; ++s) {
        const int buf = s & 1;
        if (s + 1 < nsteps) {
            stage(s + 1, buf ^ 1);
            WAITCNT_VM(4);          // wait for this tile; next tile stays in flight
        } else {
            WAITCNT_VM(0);
        }
        __builtin_amdgcn_s_barrier();

        char* base = lds + buf * 32768;
        bf16x8 ah[2], al[2], bh[4], bl[4];
        #pragma unroll
        for (int i = 0; i < 2; ++i) {
            ah[i] = *(const bf16x8*)(base + aFragOff[i]);
            al[i] = *(const bf16x8*)(base + 8192 + aFragOff[i]);
        }
        #pragma unroll
        for (int j = 0; j < 4; ++j) {
            bh[j] = *(const bf16x8*)(base + 16384 + bFragOff[j]);
            bl[j] = *(const bf16x8*)(base + 24576 + bFragOff[j]);
        }
        #pragma unroll
        for (int j = 0; j < 4; ++j)
            #pragma unroll
            for (int i = 0; i < 2; ++i) {
                acc[i][j] = __builtin_amdgcn_mfma_f32_16x16x32_bf16(al[i], bh[j], acc[i][j], 0, 0, 0);
                acc[i][j] = __builtin_amdgcn_mfma_f32_16x16x32_bf16(ah[i], bl[j], acc[i][j], 0, 0, 0);
                acc[i][j] = __builtin_amdgcn_mfma_f32_16x16x32_bf16(ah[i], bh[j], acc[i][j], 0, 0, 0);
            }
        __syncthreads();            // protect buf^1 region before restaging it
    }

    float* Cz = C + (size_t)z * zStride;
    const bool addB = (z == 0) && (bias != nullptr);
    const int rquad = (lane >> 4) * 4;
    const int cidx = lane & 15;
    #pragma unroll
    for (int i = 0; i < 2; ++i)
        #pragma unroll
        for (int j = 0; j < 4; ++j) {
            #pragma unroll
            for (int r = 0; r < 4; ++r) {
                int row = blockRow + wm * 32 + i * 16 + rquad + r;
                int col = blockCol + wn * 64 + j * 16 + cidx;
                float v = acc[i][j][r];
                if (addB) v += bias[col];
                Cz[(size_t)row * Np + col] = v;
            }
        }
}

// standalone GEMM (grid x,y,z)
__global__ __launch_bounds__(512) void gemm3_mfma(
    const unsigned short* __restrict__ Ah, const unsigned short* __restrict__ Al,
    const unsigned short* __restrict__ Bh, const unsigned short* __restrict__ Bl,
    const float* __restrict__ bias, float* __restrict__ C,
    int Kp, int Np, int Ksplit, size_t zStride)
{
    __shared__ __align__(16) char lds[65536];
    gemm_body(Ah, Al, Bh, Bl, bias, C, Kp, Np, Ksplit, zStride,
              blockIdx.x, blockIdx.y, blockIdx.z, threadIdx.x, lds);
}

// dual GEMM: blocks [0,512) = GEMM0 (8x32x2), [512,1024) = W12 (8x8x8)
__global__ __launch_bounds__(512) void gemm_dual(
    const unsigned short* __restrict__ A0h, const unsigned short* __restrict__ A0l,
    const unsigned short* __restrict__ B0h, const unsigned short* __restrict__ B0l,
    const float* __restrict__ bias0, float* __restrict__ C0,
    const unsigned short* __restrict__ A1h, const unsigned short* __restrict__ A1l,
    const unsigned short* __restrict__ B1h, const unsigned short* __restrict__ B1l,
    float* __restrict__ C1)
{
    __shared__ __align__(16) char lds[65536];
    const int b = blockIdx.x;
    if (b < 512) {
        gemm_body(A0h, A0l, B0h, B0l, bias0, C0, 1024, 1024, 512,
                  (size_t)B_SZ * 1024, b & 7, (b >> 3) & 31, b >> 8, threadIdx.x, lds);
    } else {
        const int b1 = b - 512;
        gemm_body(A1h, A1l, B1h, B1l, nullptr, C1, 2048, 1024, 256,
                  (size_t)1 << 20, b1 & 7, (b1 >> 3) & 7, b1 >> 6, threadIdx.x, lds);
    }
}

// --------------------------- unified prep kernel ---------------------------
__device__ __forceinline__ void tsplit_block(
    const float* __restrict__ W, unsigned short* __restrict__ H, unsigned short* __restrict__ L,
    int K, int N, int Kp, int bx, int by, int tid)
{
    __shared__ float tile[32][33];
    const int tx = tid & 31, ty = tid >> 5;
    const int k0 = bx * 32, n0 = by * 32;
    #pragma unroll
    for (int i = 0; i < 4; ++i) {
        int k = k0 + ty + i * 8, n = n0 + tx;
        tile[ty + i * 8][tx] = (k < K && n < N) ? W[(size_t)k * N + n] : 0.f;
    }
    __syncthreads();
    #pragma unroll
    for (int i = 0; i < 4; ++i) {
        int n = n0 + ty + i * 8, k = k0 + tx;
        float v = tile[tx][ty + i * 8];
        size_t o = (size_t)n * Kp + k;
        unsigned short h = f2bf_rne(v);
        H[o] = h;
        L[o] = f2bf_rne(v - bf2f(h));
    }
}

__global__ __launch_bounds__(256) void prep_all_kernel(
    const float* __restrict__ W0, unsigned short* __restrict__ Bt0h, unsigned short* __restrict__ Bt0l,
    const float* __restrict__ W2, unsigned short* __restrict__ Bt2h, unsigned short* __restrict__ Bt2l,
    const float* __restrict__ W3, unsigned short* __restrict__ Bt3h, unsigned short* __restrict__ Bt3l,
    const float* __restrict__ W1, unsigned short* __restrict__ W1h, unsigned short* __restrict__ W1l,
    const float* __restrict__ X, unsigned short* __restrict__ Ah, unsigned short* __restrict__ Al,
    const float* __restrict__ b1, const float* __restrict__ b2, float* __restrict__ b12,
    const float* __restrict__ b3, float* __restrict__ b3p,
    const float* __restrict__ wEnc, const float* __restrict__ wDec, float* __restrict__ G)
{
    const int bid = blockIdx.x;
    const int tid = threadIdx.x;
    if (bid < 1024) {
        tsplit_block(W0, Bt0h, Bt0l, 1000, 1024, 1024, bid & 31, bid >> 5, tid);
    } else if (bid < 3072) {
        int b = bid - 1024;
        tsplit_block(W2, Bt2h, Bt2l, 2048, 1024, 2048, b & 63, b >> 6, tid);
    } else if (bid < 4096) {
        int b = bid - 3072;
        tsplit_block(W3, Bt3h, Bt3l, 1024, 1000, 1024, b & 31, b >> 5, tid);
    } else if (bid < 5120) {
        int r = bid - 4096;
        for (int c = tid; c < 2048; c += 256) {
            float v = W1[(size_t)r * 2048 + c];
            unsigned short h = f2bf_rne(v);
            size_t o = (size_t)r * 2048 + c;
            W1h[o] = h;
            W1l[o] = f2bf_rne(v - bf2f(h));
        }
    } else if (bid < 9216) {
        int r = bid - 5120;
        for (int c = tid; c < 1024; c += 256) {
            float v = (c < 1000) ? X[(size_t)r * 1000 + c] : 0.f;
            unsigned short h = f2bf_rne(v);
            size_t o = (size_t)r * 1024 + c;
            Ah[o] = h;
            Al[o] = f2bf_rne(v - bf2f(h));
        }
    } else if (bid < 9232) {
        __shared__ float red[4][64];
        const int tx = tid & 63, ty = tid >> 6;
        const int n = (bid - 9216) * 64 + tx;
        float s = 0.f;
        for (int j = ty * 512; j < (ty + 1) * 512; ++j)
            s += b1[j] * W2[(size_t)j * 1024 + n];
        red[ty][tx] = s;
        __syncthreads();
        if (ty == 0) b12[n] = red[0][tx] + red[1][tx] + red[2][tx] + red[3][tx] + b2[n];
    } else if (bid < 9236) {
        int i = (bid - 9232) * 256 + tid;
        b3p[i] = (i < 1000) ? b3[i] : 0.f;
    } else {
        int g = tid;
        if (g < 60) {
            const float* w = (g < 30) ? (wEnc + g * 3) : (wDec + (g - 30) * 3);
            float* o = G + ((g < 30) ? g : (g - 30 + 64)) * 8;
            float phi = w[0], th = w[1], om = w[2];
            float ch = cosf(0.5f * th), sh = sinf(0.5f * th);
            float ap = 0.5f * (phi + om), am = 0.5f * (phi - om);
            float cap = cosf(ap), sap = sinf(ap);
            float cam = cosf(am), sam = sinf(am);
            o[0] =  cap * ch; o[1] = -sap * ch;
            o[2] = -cam * sh; o[3] = -sam * sh;
            o[4] =  cam * sh; o[5] = -sam * sh;
            o[6] =  cap * ch; o[7] =  sap * ch;
        }
    }
}

// -------- register-resident quantum circuit (layer-looped, small code) -----
// amp idx = (lane<<4)|reg. Wire q stride S=1<<(9-q); S<16 reg bit, else lane.
// gate index is RUNTIME-uniform (v_readlane with SGPR lane select).

template<int Q>
__device__ __forceinline__ void apply_rot_d(float (&xr)[16], float (&xi)[16],
                                            const float (&tbl)[8], int lane, int gate)
{
    float are = lane_bcast(tbl[0], gate), aim = lane_bcast(tbl[1], gate);
    float bre = lane_bcast(tbl[2], gate), bim = lane_bcast(tbl[3], gate);
    float cre = lane_bcast(tbl[4], gate), cim = lane_bcast(tbl[5], gate);
    float dre = lane_bcast(tbl[6], gate), dim_ = lane_bcast(tbl[7], gate);
    constexpr int S = 1 << (9 - Q);
    if constexpr (S < 16) {
        #pragma unroll
        for (int p = 0; p < 8; ++p) {
            int r0 = (p / S) * (2 * S) + (p % S);
            int r1 = r0 + S;
            float x0r = xr[r0], x0i = xi[r0], x1r = xr[r1], x1i = xi[r1];
            xr[r0] = are * x0r - aim * x0i + bre * x1r - bim * x1i;
            xi[r0] = are * x0i + aim * x0r + bre * x1i + bim * x1r;
            xr[r1] = cre * x0r - cim * x0i + dre * x1r - dim_ * x1i;
            xi[r1] = cre * x0i + cim * x0r + dre * x1i + dim_ * x1r;
        }
    } else {
        constexpr int M = S >> 4;
        bool bit = (lane & M) != 0;
        float pre = bit ? dre : are, pim = bit ? dim_ : aim;
        float qre = bit ? cre : bre, qim = bit ? cim : bim;
        #pragma unroll
        for (int r = 0; r < 16; ++r) {
            float ore = lane_xor<M>(xr[r]);
            float oim = lane_xor<M>(xi[r]);
            float nr = pre * xr[r] - pim * xi[r] + qre * ore - qim * oim;
            float ni = pre * xi[r] + pim * xr[r] + qre * oim + qim * ore;
            xr[r] = nr; xi[r] = ni;
        }
    }
}

template<int Q>
__device__ __forceinline__ void rots_d(float (&xr)[16], float (&xi)[16],
                                       const float (&tbl)[8], int lane, int base) {
    apply_rot_d<Q>(xr, xi, tbl, lane, base + Q);
    if constexpr (Q < 9) rots_d<Q + 1>(xr, xi, tbl, lane, base);
}

template<int C, int T>
__device__ __forceinline__ void apply_cnot(float (&xr)[16], float (&xi)[16], int lane)
{
    constexpr int SC = 1 << (9 - C), ST = 1 << (9 - T);
    if constexpr (SC < 16 && ST < 16) {
        #pragma unroll
        for (int r = 0; r < 16; ++r) {
            if ((r & SC) && !(r & ST)) {
                int j = r | ST;
                float t;
                t = xr[r]; xr[r] = xr[j]; xr[j] = t;
                t = xi[r]; xi[r] = xi[j]; xi[j] = t;
            }
        }
    } else if constexpr (SC < 16) {
        constexpr int MT = ST >> 4;
        #pragma unroll
        for (int r = 0; r < 16; ++r) {
            if (r & SC) {
                xr[r] = lane_xor<MT>(xr[r]);
                xi[r] = lane_xor<MT>(xi[r]);
            }
        }
    } else if constexpr (ST < 16) {
        constexpr int MC = SC >> 4;
        bool bit = (lane & MC) != 0;
        #pragma unroll
        for (int r = 0; r < 16; ++r) {
            if (!(r & ST)) {
                int j = r | ST;
                float a0 = xr[r], a1 = xr[j];
                xr[r] = bit ? a1 : a0;  xr[j] = bit ? a0 : a1;
                float b0 = xi[r], b1 = xi[j];
                xi[r] = bit ? b1 : b0;  xi[j] = bit ? b0 : b1;
            }
        }
    } else {
        constexpr int MC = SC >> 4, MT = ST >> 4;
        bool bit = (lane & MC) != 0;
        #pragma unroll
        for (int r = 0; r < 16; ++r) {
            float o = lane_xor<MT>(xr[r]);
            xr[r] = bit ? o : xr[r];
            float oi = lane_xor<MT>(xi[r]);
            xi[r] = bit ? oi : xi[r];
        }
    }
}

template<int L, int Q>
__device__ __forceinline__ void cnots(float (&xr)[16], float (&xi)[16], int lane) {
    constexpr int R = (L % 9) + 1;
    apply_cnot<Q, (Q + R) % 10>(xr, xi, lane);
    if constexpr (Q < 9) cnots<L, Q + 1>(xr, xi, lane);
}

__device__ __forceinline__ void circuit_body(
    const float* __restrict__ X0, const float* __restrict__ X1,
    unsigned short* __restrict__ Ph, unsigned short* __restrict__ Pl,
    const float* __restrict__ G, int item, int lane)
{
    const size_t base = (size_t)item * 1024 + lane * 16;

    float tbl[8];
    {
        const float4* gp = (const float4*)(G + lane * 8);
        float4 t0 = gp[0], t1 = gp[1];
        tbl[0] = t0.x; tbl[1] = t0.y; tbl[2] = t0.z; tbl[3] = t0.w;
        tbl[4] = t1.x; tbl[5] = t1.y; tbl[6] = t1.z; tbl[7] = t1.w;
    }

    float xr[16], xi[16];
    const float4* xb0 = (const float4*)(X0 + base);
    const float4* xb1 = (const float4*)(X1 + base);
    #pragma unroll
    for (int v = 0; v < 4; ++v) {
        float4 f = xb0[v], g = xb1[v];
        xr[v * 4 + 0] = f.x + g.x; xr[v * 4 + 1] = f.y + g.y;
        xr[v * 4 + 2] = f.z + g.z; xr[v * 4 + 3] = f.w + g.w;
    }
    #pragma unroll
    for (int r = 0; r < 16; ++r) xi[r] = 0.f;

    float nrm = 0.f;
    #pragma unroll
    for (int r = 0; r < 16; ++r) nrm += xr[r] * xr[r];
    nrm += lane_xor<1>(nrm);
    nrm += lane_xor<2>(nrm);
    nrm += lane_xor<4>(nrm);
    nrm += lane_xor<8>(nrm);
    nrm += lane_xor<16>(nrm);
    nrm += lane_xor<32>(nrm);
    float inv = 1.0f / sqrtf(nrm);
    #pragma unroll
    for (int r = 0; r < 16; ++r) xr[r] *= inv;

    // layer loop kept rolled: code ~2.4x smaller than full unroll (I$ fit)
    #pragma clang loop unroll(disable)
    for (int l = 0; l < 3; ++l) {
        rots_d<0>(xr, xi, tbl, lane, l * 10);
        if (l == 0)      cnots<0, 0>(xr, xi, lane);
        else if (l == 1) cnots<1, 0>(xr, xi, lane);
        else             cnots<2, 0>(xr, xi, lane);
    }

    u16x8 h[2], lo[2];
    #pragma unroll
    for (int r = 0; r < 16; ++r) {
        float p = xr[r] * xr[r] + xi[r] * xi[r];
        unsigned short hh = f2bf_rne(p);
        h[r >> 3][r & 7] = hh;
        lo[r >> 3][r & 7] = f2bf_rne(p - bf2f(hh));
    }
    *(u16x8*)(Ph + base) = h[0];
    *(u16x8*)(Ph + base + 8) = h[1];
    *(u16x8*)(Pl + base) = lo[0];
    *(u16x8*)(Pl + base + 8) = lo[1];
}

// standalone circuit (decoder): grid 1024 x 256
__global__ __launch_bounds__(256, 4) void circuit_reg_kernel(
    const float* __restrict__ X0, const float* __restrict__ X1,
    unsigned short* __restrict__ Ph, unsigned short* __restrict__ Pl,
    const float* __restrict__ G)
{
    circuit_body(X0, X1, Ph, Pl, G,
                 blockIdx.x * 4 + (threadIdx.x >> 6), threadIdx.x & 63);
}

// fused: blocks [0,1024) = tsplit8 (W12 partial-sum transpose-split),
//        blocks [1024,2048) = circuit enc
__global__ __launch_bounds__(256, 4) void fused_ts_circ_kernel(
    const float* __restrict__ P12, unsigned short* __restrict__ H, unsigned short* __restrict__ L,
    const float* __restrict__ X0, const float* __restrict__ X1,
    unsigned short* __restrict__ Ph, unsigned short* __restrict__ Pl,
    const float* __restrict__ G)
{
    __shared__ float tile[32][33];
    const int bid = blockIdx.x;
    const int tid = threadIdx.x;
    if (bid < 1024) {
        const int tx = tid & 31, ty = tid >> 5;
        const int k0 = (bid & 31) * 32, n0 = (bid >> 5) * 32;
        #pragma unroll
        for (int i = 0; i < 4; ++i) {
            int k = k0 + ty + i * 8, n = n0 + tx;
            size_t o = (size_t)k * 1024 + n;
            float s = 0.f;
            #pragma unroll
            for (int zz = 0; zz < 8; ++zz) s += P12[o + ((size_t)zz << 20)];
            tile[ty + i * 8][tx] = s;
        }
        __syncthreads();
        #pragma unroll
        for (int i = 0; i < 4; ++i) {
            int n = n0 + ty + i * 8, k = k0 + tx;
            float v = tile[tx][ty + i * 8];
            size_t o = (size_t)n * 1024 + k;
            unsigned short h = f2bf_rne(v);
            H[o] = h;
            L[o] = f2bf_rne(v - bf2f(h));
        }
    } else {
        circuit_body(X0, X1, Ph, Pl, G,
                     (bid - 1024) * 4 + (tid >> 6), tid & 63);
    }
}

// --------------- abs + row-normalize (2 partials, single pass) -------------
__global__ __launch_bounds__(256) void absnorm_kernel(
    const float* __restrict__ P, size_t ZS, float* __restrict__ out, int N)
{
    __shared__ float red[4];
    const int row = blockIdx.x;
    const int tid = threadIdx.x;
    const size_t rb = (size_t)row * 1024 + tid * 4;

    float4 a = *(const float4*)(P + rb);
    float4 b = *(const float4*)(P + ZS + rb);
    float x[4] = { a.x + b.x, a.y + b.y, a.z + b.z, a.w + b.w };

    const int c0 = tid * 4;
    float s = 0.f;
    #pragma unroll
    for (int j = 0; j < 4; ++j) if (c0 + j < N) s += fabsf(x[j]);
    #pragma unroll
    for (int off = 32; off > 0; off >>= 1) s += __shfl_down(s, off);
    if ((tid & 63) == 0) red[tid >> 6] = s;
    __syncthreads();
    float inv = 1.0f / (red[0] + red[1] + red[2] + red[3]);
    #pragma unroll
    for (int j = 0; j < 4; ++j)
        if (c0 + j < N) out[(size_t)row * N + c0 + j] = fabsf(x[j]) * inv;
}

// ---------------------------------------------------------------------------
extern "C" void kernel_launch(void* const* d_in, const int* in_sizes, int n_in,
                              void* d_out, int out_size, void* d_ws, size_t ws_size,
                              hipStream_t stream)
{
    const float* inputs = (const float*)d_in[0];
    const float* wEnc   = (const float*)d_in[1];
    const float* wDec   = (const float*)d_in[2];
    const float* W0     = (const float*)d_in[3];
    const float* b0     = (const float*)d_in[4];
    const float* W1     = (const float*)d_in[5];
    const float* b1     = (const float*)d_in[6];
    const float* W2     = (const float*)d_in[7];
    const float* b2     = (const float*)d_in[8];
    const float* W3     = (const float*)d_in[9];
    const float* b3     = (const float*)d_in[10];
    float* out = (float*)d_out;

    char* w = (char*)d_ws;
    auto alloc = [&](size_t bytes) { char* p = w; w += (bytes + 255) & ~(size_t)255; return p; };

    unsigned short* Bt0h  = (unsigned short*)alloc((size_t)1024 * 1024 * 2);
    unsigned short* Bt0l  = (unsigned short*)alloc((size_t)1024 * 1024 * 2);
    unsigned short* Bt2h  = (unsigned short*)alloc((size_t)1024 * 2048 * 2);
    unsigned short* Bt2l  = (unsigned short*)alloc((size_t)1024 * 2048 * 2);
    unsigned short* Bt3h  = (unsigned short*)alloc((size_t)1024 * 1024 * 2);
    unsigned short* Bt3l  = (unsigned short*)alloc((size_t)1024 * 1024 * 2);
    unsigned short* Bt12h = (unsigned short*)alloc((size_t)1024 * 1024 * 2);
    unsigned short* Bt12l = (unsigned short*)alloc((size_t)1024 * 1024 * 2);
    unsigned short* W1h   = (unsigned short*)alloc((size_t)1024 * 2048 * 2);
    unsigned short* W1l   = (unsigned short*)alloc((size_t)1024 * 2048 * 2);
    float*          b3p   = (float*)alloc(1024 * 4);
    float*          b12   = (float*)alloc(1024 * 4);
    float*          G     = (float*)alloc(2 * 512 * 4);   // enc @ G, dec @ G+512
    unsigned short* Ah    = (unsigned short*)alloc((size_t)B_SZ * 1024 * 2);
    unsigned short* Al    = (unsigned short*)alloc((size_t)B_SZ * 1024 * 2);
    unsigned short* ph    = (unsigned short*)alloc((size_t)B_SZ * 1024 * 2);
    unsigned short* pl    = (unsigned short*)alloc((size_t)B_SZ * 1024 * 2);
    float*          P     = (float*)alloc((size_t)2 * B_SZ * 1024 * 4);  // split-K partials
    float*          P12   = (float*)alloc((size_t)8 * 1024 * 1024 * 4);  // W12 partials (own buffer)
    const size_t ZS = (size_t)B_SZ * 1024;

    dim3 blk256(256);

    // ---- per-call prep: ONE dispatch ----
    prep_all_kernel<<<9237, blk256, 0, stream>>>(
        W0, Bt0h, Bt0l, W2, Bt2h, Bt2l, W3, Bt3h, Bt3l, W1, W1h, W1l,
        inputs, Ah, Al, b1, b2, b12, b3, b3p, wEnc, wDec, G);

    // ---- GEMM0 || W12  (disjoint outputs P / P12) ----
    gemm_dual<<<1024, 512, 0, stream>>>(
        Ah, Al, Bt0h, Bt0l, b0, P,
        W1h, W1l, Bt2h, Bt2l, P12);

    // ---- tsplit8(P12->Bt12) || circuit-enc ----
    fused_ts_circ_kernel<<<2048, blk256, 0, stream>>>(
        P12, Bt12h, Bt12l, P, P + ZS, ph, pl, G);

    // ---- x2 = p @ W12 + b12 ----
    gemm3_mfma<<<dim3(8, 32, 2), 512, 0, stream>>>(
        ph, pl, Bt12h, Bt12l, b12, P, 1024, 1024, 512, ZS);

    // ---- circuit-dec ----
    circuit_reg_kernel<<<1024, blk256, 0, stream>>>(P, P + ZS, ph, pl, G + 512);

    // ---- x3 = p @ W3 + b3 ----
    gemm3_mfma<<<dim3(8, 32, 2), 512, 0, stream>>>(
        ph, pl, Bt3h, Bt3l, b3p, P, 1024, 1024, 512, ZS);

    absnorm_kernel<<<B_SZ, blk256, 0, stream>>>(P, ZS, out, 1000);
}